// Round 1
// baseline (811.740 us; speedup 1.0000x reference)
//
#include <hip/hip_runtime.h>
#include <hip/hip_bf16.h>
#include <cstdint>

// Problem constants
#define DIMC  256
#define NH    8
#define HD    32
#define NPIX  2304       // 48*48
#define BATCH 2
#define NSPLIT 4
#define KEYS_PER_SPLIT 576   // 2304 / NSPLIT
#define TK 32                // key tile inside attention

// ---------------------------------------------------------------------------
// Pool: x_avg = (x + box3/9 + box5/25 + box7/49) / 4, zero padding,
// count_include_pad=True. One block per (b,c) plane, separable in LDS.
// ---------------------------------------------------------------------------
__global__ __launch_bounds__(256) void pool_kernel(const float* __restrict__ x,
                                                   float* __restrict__ xavg) {
  const int plane = blockIdx.x;                 // b*256 + c
  const float* xp = x + (size_t)plane * NPIX;
  __shared__ float sx[NPIX];
  __shared__ float h3[NPIX], h5[NPIX], h7[NPIX];
  const int t = threadIdx.x;
#pragma unroll
  for (int r = 0; r < 9; ++r) sx[r * 256 + t] = xp[r * 256 + t];
  __syncthreads();
#pragma unroll
  for (int r = 0; r < 9; ++r) {
    int p = r * 256 + t;
    int i = p / 48, j = p - i * 48;
    float a3 = 0.f, a5 = 0.f, a7 = 0.f;
#pragma unroll
    for (int dj = -3; dj <= 3; ++dj) {
      int jj = j + dj;
      if (jj < 0 || jj >= 48) continue;
      float v = sx[i * 48 + jj];
      a7 += v;
      if (dj >= -2 && dj <= 2) a5 += v;
      if (dj >= -1 && dj <= 1) a3 += v;
    }
    h3[p] = a3; h5[p] = a5; h7[p] = a7;
  }
  __syncthreads();
#pragma unroll
  for (int r = 0; r < 9; ++r) {
    int p = r * 256 + t;
    int i = p / 48, j = p - i * 48;
    float b3 = 0.f, b5 = 0.f, b7 = 0.f;
#pragma unroll
    for (int di = -3; di <= 3; ++di) {
      int ii = i + di;
      if (ii < 0 || ii >= 48) continue;
      int q = ii * 48 + j;
      b7 += h7[q];
      if (di >= -2 && di <= 2) b5 += h5[q];
      if (di >= -1 && di <= 1) b3 += h3[q];
    }
    xavg[(size_t)plane * NPIX + p] =
        0.25f * (sx[p] + b3 * (1.f / 9.f) + b5 * (1.f / 25.f) + b7 * (1.f / 49.f));
  }
}

// ---------------------------------------------------------------------------
// 1x1-conv GEMM: Out[b][o][n] = sum_c W[o][c]*In[b][c][n] + bias[o]
// Tiles: BO=64 (o), BN=128 (n), BK=32. 256 threads, 4x8 outputs/thread.
// ---------------------------------------------------------------------------
#define BO 64
#define BN 128
#define BK 32
__global__ __launch_bounds__(256) void gemm1x1(const float* __restrict__ W,
                                               const float* __restrict__ bias,
                                               const float* __restrict__ In,
                                               float* __restrict__ Out,
                                               int O, int C, int N) {
  const int b  = blockIdx.z;
  const int o0 = blockIdx.y * BO;
  const int n0 = blockIdx.x * BN;
  const float* Inb = In + (size_t)b * C * N;
  float* Outb = Out + (size_t)b * O * N;
  __shared__ __align__(16) float Wt[BK][BO];   // Wt[k][o]
  __shared__ __align__(16) float It[BK][BN];   // It[k][n]
  const int tid = threadIdx.x;
  const int to = tid >> 4;   // 0..15 -> o group (4 consecutive o)
  const int tn = tid & 15;   // 0..15 -> n group (4 consecutive n, x2 at +64)
  float acc[4][8];
#pragma unroll
  for (int i = 0; i < 4; ++i)
#pragma unroll
    for (int j = 0; j < 8; ++j) acc[i][j] = 0.f;

  for (int c0 = 0; c0 < C; c0 += BK) {
    __syncthreads();
    {   // load W tile (transposed): thread: o=tid/4, k=(tid%4)*8 .. +7
      int o = tid >> 2;
      int k = (tid & 3) * 8;
      const float* wp = W + (size_t)(o0 + o) * C + c0 + k;
      float4 w0 = *(const float4*)wp;
      float4 w1 = *(const float4*)(wp + 4);
      Wt[k + 0][o] = w0.x; Wt[k + 1][o] = w0.y; Wt[k + 2][o] = w0.z; Wt[k + 3][o] = w0.w;
      Wt[k + 4][o] = w1.x; Wt[k + 5][o] = w1.y; Wt[k + 6][o] = w1.z; Wt[k + 7][o] = w1.w;
    }
    {   // load In tile: thread: k=tid/8, n=(tid%8)*16 .. +15
      int k = tid >> 3;
      int n = (tid & 7) * 16;
      const float* ip = Inb + (size_t)(c0 + k) * N + n0 + n;
      float4* dst = (float4*)&It[k][n];
      const float4* src = (const float4*)ip;
      dst[0] = src[0]; dst[1] = src[1]; dst[2] = src[2]; dst[3] = src[3];
    }
    __syncthreads();
#pragma unroll
    for (int k = 0; k < BK; ++k) {
      float4 wv = *(const float4*)&Wt[k][to * 4];
      float4 i0 = *(const float4*)&It[k][tn * 4];
      float4 i1 = *(const float4*)&It[k][tn * 4 + 64];
      float wa[4] = {wv.x, wv.y, wv.z, wv.w};
      float ia[8] = {i0.x, i0.y, i0.z, i0.w, i1.x, i1.y, i1.z, i1.w};
#pragma unroll
      for (int i = 0; i < 4; ++i)
#pragma unroll
        for (int j = 0; j < 8; ++j) acc[i][j] += wa[i] * ia[j];
    }
  }
#pragma unroll
  for (int i = 0; i < 4; ++i) {
    int o = o0 + to * 4 + i;
    float bv = bias[o];
    float* op = Outb + (size_t)o * N + n0 + tn * 4;
    float4 r0 = {acc[i][0] + bv, acc[i][1] + bv, acc[i][2] + bv, acc[i][3] + bv};
    float4 r1 = {acc[i][4] + bv, acc[i][5] + bv, acc[i][6] + bv, acc[i][7] + bv};
    *(float4*)op = r0;
    *(float4*)(op + 64) = r1;
  }
}

// ---------------------------------------------------------------------------
// Attention (fp32, online softmax, K-split x4). One thread per query row.
// qb:  [B][256][N]   (channel o = head*32+dd)
// kvb: [B][512][N]   (k at o<256, v at o>=256)
// Stores UNNORMALIZED partials: part_o[row][split][32], part_ml[row][split][2]
// ---------------------------------------------------------------------------
__global__ __launch_bounds__(64) void attn_kernel(const float* __restrict__ qb,
                                                  const float* __restrict__ kvb,
                                                  float* __restrict__ part_o,
                                                  float* __restrict__ part_ml) {
  const int rt    = blockIdx.x;   // 0..575 row tile (64 rows, uniform b/head)
  const int split = blockIdx.y;   // 0..NSPLIT-1
  const int t = threadIdx.x;
  const int row = rt * 64 + t;          // (b*8+head)*2304 + n
  const int n   = row % NPIX;
  const int bh  = row / NPIX;
  const int head = bh & 7, b = bh >> 3;

  const float* qg = qb + ((size_t)b * DIMC + head * HD) * NPIX + n;
  const float* kg = kvb + ((size_t)b * 2 * DIMC + head * HD) * NPIX;
  const float* vg = kg + (size_t)DIMC * NPIX;

  const float qscale = 0.17677669529663689f * 1.4426950408889634f; // SCALE*log2(e)
  float qr[HD];
#pragma unroll
  for (int dd = 0; dd < HD; ++dd) qr[dd] = qg[(size_t)dd * NPIX] * qscale;

  __shared__ __align__(16) float kl[TK * 36];   // [j][dd], row stride 36 (144B, 16B-aligned)
  __shared__ __align__(16) float vl[TK * 36];

  float m = -1e30f, l = 0.f;
  float o[HD];
#pragma unroll
  for (int dd = 0; dd < HD; ++dd) o[dd] = 0.f;

  int j0 = split * KEYS_PER_SPLIT;
  for (int tile = 0; tile < KEYS_PER_SPLIT / TK; ++tile, j0 += TK) {
    __syncthreads();
#pragma unroll
    for (int r = 0; r < 16; ++r) {      // stage K/V tile: [j][dd] layout
      int dd = 2 * r + (t >> 5);
      int j  = t & 31;
      kl[j * 36 + dd] = kg[(size_t)dd * NPIX + j0 + j];
      vl[j * 36 + dd] = vg[(size_t)dd * NPIX + j0 + j];
    }
    __syncthreads();
    float s[TK];
#pragma unroll
    for (int j = 0; j < TK; ++j) {
      const float* kp = &kl[j * 36];
      float acc = 0.f;
#pragma unroll
      for (int dd = 0; dd < HD; ++dd) acc += qr[dd] * kp[dd];
      s[j] = acc;
    }
    float tm = m;
#pragma unroll
    for (int j = 0; j < TK; ++j) tm = fmaxf(tm, s[j]);
    float alpha = exp2f(m - tm);
    m = tm;
    l *= alpha;
#pragma unroll
    for (int dd = 0; dd < HD; ++dd) o[dd] *= alpha;
#pragma unroll
    for (int j = 0; j < TK; ++j) {
      float p = exp2f(s[j] - m);
      l += p;
      const float* vp = &vl[j * 36];
#pragma unroll
      for (int dd = 0; dd < HD; ++dd) o[dd] += p * vp[dd];
    }
  }
  const size_t base = ((size_t)row * NSPLIT + split) * HD;
#pragma unroll
  for (int dd = 0; dd < HD; ++dd) part_o[base + dd] = o[dd];
  part_ml[(size_t)row * 2 * NSPLIT + split * 2]     = m;
  part_ml[(size_t)row * 2 * NSPLIT + split * 2 + 1] = l;
}

// ---------------------------------------------------------------------------
// Merge K-splits and write the SCRAMBLED z layout:
// z[b][c][p] with c=n/9, p=(n%9)*256 + head*32 + dd  (torch flat-reshape)
// ---------------------------------------------------------------------------
__global__ __launch_bounds__(256) void attn_merge(const float* __restrict__ part_o,
                                                  const float* __restrict__ part_ml,
                                                  float* __restrict__ z) {
  const int idx = blockIdx.x * 256 + threadIdx.x;   // row id, 0..36863
  const int n  = idx % NPIX;
  const int bh = idx / NPIX;
  const int head = bh & 7, b = bh >> 3;
  float mm[NSPLIT], ll[NSPLIT];
  float m = -1e30f;
#pragma unroll
  for (int s = 0; s < NSPLIT; ++s) {
    mm[s] = part_ml[(size_t)idx * 2 * NSPLIT + s * 2];
    ll[s] = part_ml[(size_t)idx * 2 * NSPLIT + s * 2 + 1];
    m = fmaxf(m, mm[s]);
  }
  float w[NSPLIT];
  float L = 0.f;
#pragma unroll
  for (int s = 0; s < NSPLIT; ++s) {
    w[s] = exp2f(mm[s] - m);
    L += ll[s] * w[s];
  }
  const float inv = 1.f / L;
  float* zp = z + ((size_t)b * DIMC + n / 9) * NPIX + (n % 9) * DIMC + head * HD;
#pragma unroll
  for (int dd = 0; dd < HD; ++dd) {
    float acc = 0.f;
#pragma unroll
    for (int s = 0; s < NSPLIT; ++s)
      acc += part_o[((size_t)idx * NSPLIT + s) * HD + dd] * w[s];
    zp[dd] = acc * inv;
  }
}

// ---------------------------------------------------------------------------
extern "C" void kernel_launch(void* const* d_in, const int* in_sizes, int n_in,
                              void* d_out, int out_size, void* d_ws, size_t ws_size,
                              hipStream_t stream) {
  const float* x      = (const float*)d_in[0];
  const float* q_w    = (const float*)d_in[1];
  const float* q_b    = (const float*)d_in[2];
  const float* kv_w   = (const float*)d_in[3];
  const float* kv_b   = (const float*)d_in[4];
  const float* proj_w = (const float*)d_in[5];
  const float* proj_b = (const float*)d_in[6];
  float* out = (float*)d_out;

  // workspace carve-up (floats): ~43.6 MB total
  float* ws      = (float*)d_ws;
  float* xavg    = ws;                                          // B*256*N
  float* qb      = xavg    + (size_t)BATCH * DIMC * NPIX;       // B*256*N
  float* kvb     = qb      + (size_t)BATCH * DIMC * NPIX;       // B*512*N
  float* z       = kvb     + (size_t)BATCH * 2 * DIMC * NPIX;   // B*256*N
  float* part_o  = z       + (size_t)BATCH * DIMC * NPIX;       // 36864*4*32
  float* part_ml = part_o  + (size_t)BATCH * NH * NPIX * NSPLIT * HD; // 36864*8

  pool_kernel<<<BATCH * DIMC, 256, 0, stream>>>(x, xavg);
  gemm1x1<<<dim3(NPIX / BN, 256 / BO, BATCH), 256, 0, stream>>>(q_w, q_b, x, qb, 256, 256, NPIX);
  gemm1x1<<<dim3(NPIX / BN, 512 / BO, BATCH), 256, 0, stream>>>(kv_w, kv_b, xavg, kvb, 512, 256, NPIX);
  attn_kernel<<<dim3(BATCH * NH * NPIX / 64, NSPLIT), 64, 0, stream>>>(qb, kvb, part_o, part_ml);
  attn_merge<<<dim3(BATCH * NH * NPIX / 256), 256, 0, stream>>>(part_o, part_ml, z);
  gemm1x1<<<dim3(NPIX / BN, 256 / BO, BATCH), 256, 0, stream>>>(proj_w, proj_b, z, out, 256, 256, NPIX);
}

// Round 2
// 290.195 us; speedup vs baseline: 2.7972x; 2.7972x over previous
//
#include <hip/hip_runtime.h>
#include <hip/hip_bf16.h>
#include <cstdint>

// Problem constants
#define DIMC  256
#define NH    8
#define HD    32
#define NPIX  2304       // 48*48
#define BATCH 2
#define NSPLIT 2
#define KPS   1152       // keys per split
#define KT    32         // key tile per iteration

typedef short s16x8 __attribute__((ext_vector_type(8)));
typedef short s16x4 __attribute__((ext_vector_type(4)));
typedef float f32x4 __attribute__((ext_vector_type(4)));

__device__ inline short f2bf(float x) {            // RNE fp32 -> bf16 bits
  union { float f; uint32_t u; } a; a.f = x;
  uint32_t r = a.u + 0x7fffu + ((a.u >> 16) & 1u);
  return (short)(r >> 16);
}
__device__ inline float bf2f(short b) {
  union { uint32_t u; float f; } a; a.u = ((uint32_t)(uint16_t)b) << 16;
  return a.f;
}

// ---------------------------------------------------------------------------
// Pool: x_avg = (x + box3/9 + box5/25 + box7/49) / 4 (zero pad, include_pad)
// ---------------------------------------------------------------------------
__global__ __launch_bounds__(256) void pool_kernel(const float* __restrict__ x,
                                                   float* __restrict__ xavg) {
  const int plane = blockIdx.x;
  const float* xp = x + (size_t)plane * NPIX;
  __shared__ float sx[NPIX];
  __shared__ float h3[NPIX], h5[NPIX], h7[NPIX];
  const int t = threadIdx.x;
#pragma unroll
  for (int r = 0; r < 9; ++r) sx[r * 256 + t] = xp[r * 256 + t];
  __syncthreads();
#pragma unroll
  for (int r = 0; r < 9; ++r) {
    int p = r * 256 + t;
    int i = p / 48, j = p - i * 48;
    float a3 = 0.f, a5 = 0.f, a7 = 0.f;
#pragma unroll
    for (int dj = -3; dj <= 3; ++dj) {
      int jj = j + dj;
      if (jj < 0 || jj >= 48) continue;
      float v = sx[i * 48 + jj];
      a7 += v;
      if (dj >= -2 && dj <= 2) a5 += v;
      if (dj >= -1 && dj <= 1) a3 += v;
    }
    h3[p] = a3; h5[p] = a5; h7[p] = a7;
  }
  __syncthreads();
#pragma unroll
  for (int r = 0; r < 9; ++r) {
    int p = r * 256 + t;
    int i = p / 48, j = p - i * 48;
    float b3 = 0.f, b5 = 0.f, b7 = 0.f;
#pragma unroll
    for (int di = -3; di <= 3; ++di) {
      int ii = i + di;
      if (ii < 0 || ii >= 48) continue;
      int q = ii * 48 + j;
      b7 += h7[q];
      if (di >= -2 && di <= 2) b5 += h5[q];
      if (di >= -1 && di <= 1) b3 += h3[q];
    }
    xavg[(size_t)plane * NPIX + p] =
        0.25f * (sx[p] + b3 * (1.f / 9.f) + b5 * (1.f / 25.f) + b7 * (1.f / 49.f));
  }
}

// ---------------------------------------------------------------------------
// fp32 1x1-conv GEMM (unchanged from R1)
// ---------------------------------------------------------------------------
#define BO 64
#define BN 128
#define BK 32
__global__ __launch_bounds__(256) void gemm1x1(const float* __restrict__ W,
                                               const float* __restrict__ bias,
                                               const float* __restrict__ In,
                                               float* __restrict__ Out,
                                               int O, int C, int N) {
  const int b  = blockIdx.z;
  const int o0 = blockIdx.y * BO;
  const int n0 = blockIdx.x * BN;
  const float* Inb = In + (size_t)b * C * N;
  float* Outb = Out + (size_t)b * O * N;
  __shared__ __align__(16) float Wt[BK][BO];
  __shared__ __align__(16) float It[BK][BN];
  const int tid = threadIdx.x;
  const int to = tid >> 4;
  const int tn = tid & 15;
  float acc[4][8];
#pragma unroll
  for (int i = 0; i < 4; ++i)
#pragma unroll
    for (int j = 0; j < 8; ++j) acc[i][j] = 0.f;

  for (int c0 = 0; c0 < C; c0 += BK) {
    __syncthreads();
    {
      int o = tid >> 2;
      int k = (tid & 3) * 8;
      const float* wp = W + (size_t)(o0 + o) * C + c0 + k;
      float4 w0 = *(const float4*)wp;
      float4 w1 = *(const float4*)(wp + 4);
      Wt[k + 0][o] = w0.x; Wt[k + 1][o] = w0.y; Wt[k + 2][o] = w0.z; Wt[k + 3][o] = w0.w;
      Wt[k + 4][o] = w1.x; Wt[k + 5][o] = w1.y; Wt[k + 6][o] = w1.z; Wt[k + 7][o] = w1.w;
    }
    {
      int k = tid >> 3;
      int n = (tid & 7) * 16;
      const float* ip = Inb + (size_t)(c0 + k) * N + n0 + n;
      float4* dst = (float4*)&It[k][n];
      const float4* src = (const float4*)ip;
      dst[0] = src[0]; dst[1] = src[1]; dst[2] = src[2]; dst[3] = src[3];
    }
    __syncthreads();
#pragma unroll
    for (int k = 0; k < BK; ++k) {
      float4 wv = *(const float4*)&Wt[k][to * 4];
      float4 i0 = *(const float4*)&It[k][tn * 4];
      float4 i1 = *(const float4*)&It[k][tn * 4 + 64];
      float wa[4] = {wv.x, wv.y, wv.z, wv.w};
      float ia[8] = {i0.x, i0.y, i0.z, i0.w, i1.x, i1.y, i1.z, i1.w};
#pragma unroll
      for (int i = 0; i < 4; ++i)
#pragma unroll
        for (int j = 0; j < 8; ++j) acc[i][j] += wa[i] * ia[j];
    }
  }
#pragma unroll
  for (int i = 0; i < 4; ++i) {
    int o = o0 + to * 4 + i;
    float bv = bias[o];
    float* op = Outb + (size_t)o * N + n0 + tn * 4;
    float4 r0 = {acc[i][0] + bv, acc[i][1] + bv, acc[i][2] + bv, acc[i][3] + bv};
    float4 r1 = {acc[i][4] + bv, acc[i][5] + bv, acc[i][6] + bv, acc[i][7] + bv};
    *(float4*)op = r0;
    *(float4*)(op + 64) = r1;
  }
}

// ---------------------------------------------------------------------------
// Transpose+split convert: src [b][srcC][N] channels ch0+h*32.. -> dst [bh][n][32]
// bf16 hi/lo, optional scale. One block per (n-block of 64, bh).
// ---------------------------------------------------------------------------
__global__ __launch_bounds__(256) void convert_t(const float* __restrict__ src,
                                                 short* __restrict__ dhi,
                                                 short* __restrict__ dlo,
                                                 int srcC, int ch0, float scale) {
  const int n0 = blockIdx.x * 64;
  const int bh = blockIdx.y;
  const int b = bh >> 3, h = bh & 7;
  const int t = threadIdx.x;
  __shared__ __align__(16) short Lhi[64 * 40], Llo[64 * 40];
  {
    const int d = t >> 3;
    const int nn = (t & 7) * 8;
    const float* sp = src + ((size_t)b * srcC + ch0 + h * HD + d) * NPIX + n0 + nn;
#pragma unroll
    for (int i = 0; i < 8; ++i) {
      float x = sp[i] * scale;
      short hi = f2bf(x);
      short lo = f2bf(x - bf2f(hi));
      Lhi[(nn + i) * 40 + d] = hi;
      Llo[(nn + i) * 40 + d] = lo;
    }
  }
  __syncthreads();
  {
    const int n = t >> 2;
    const int dg = (t & 3) * 8;
    s16x8 vh = *(const s16x8*)&Lhi[n * 40 + dg];
    s16x8 vl = *(const s16x8*)&Llo[n * 40 + dg];
    size_t off = ((size_t)bh * NPIX + n0 + n) * HD + dg;
    *(s16x8*)(dhi + off) = vh;
    *(s16x8*)(dlo + off) = vl;
  }
}

// ---------------------------------------------------------------------------
// V convert (no transpose): kvb[b][256+c][n] -> Vhi/Vlo [bh][d][n] bf16 hi/lo
// ---------------------------------------------------------------------------
__global__ __launch_bounds__(256) void convert_v(const float* __restrict__ kvb,
                                                 short* __restrict__ vhi,
                                                 short* __restrict__ vlo) {
  const int idx = (blockIdx.x * 256 + threadIdx.x) * 4;   // over B*256*N
  const int b = idx / (DIMC * NPIX);
  const int r = idx - b * (DIMC * NPIX);
  const float* sp = kvb + ((size_t)b * 2 * DIMC + DIMC) * NPIX + r;
  float4 x = *(const float4*)sp;
  float v[4] = {x.x, x.y, x.z, x.w};
  s16x4 hi, lo;
#pragma unroll
  for (int i = 0; i < 4; ++i) {
    hi[i] = f2bf(v[i]);
    lo[i] = f2bf(v[i] - bf2f(hi[i]));
  }
  *(s16x4*)(vhi + idx) = hi;
  *(s16x4*)(vlo + idx) = lo;
}

// ---------------------------------------------------------------------------
// MFMA flash attention, transposed (S^T = K·Q^T, O^T = V^T·P^T).
// Block = 4 waves; wave w owns q-rows qblk*64 + w*16 .. +15, iterates KPS keys.
// Q/K hi+lo (3 MFMAs per 16-key slice), P hi-only, V hi+lo.
// C-layout: col = lane&15 (= q), row = (lane>>4)*4 + reg.
// A-layout: m = lane&15, k = (lane>>4)*8 + j.  B-layout: n = lane&15, same k.
// ---------------------------------------------------------------------------
__global__ __launch_bounds__(256) void attn_mfma(
    const short* __restrict__ Qhi, const short* __restrict__ Qlo,   // [bh][n][32]
    const short* __restrict__ Khi, const short* __restrict__ Klo,   // [bh][n][32]
    const short* __restrict__ Vhi, const short* __restrict__ Vlo,   // [bh][32][N]
    float* __restrict__ part_o,    // [row][NSPLIT][32]
    float* __restrict__ part_ml) { // [row][NSPLIT][2]
  const int qblk  = blockIdx.x % 36;
  const int bh    = blockIdx.x / 36;
  const int split = blockIdx.y;
  const int tid = threadIdx.x;
  const int wave = tid >> 6, lane = tid & 63;
  const int g = lane >> 4, q = lane & 15;
  const int qrow = qblk * 64 + wave * 16 + q;

  // per-wave private P^T scratch: [q][j] bf16, row stride 40 (80B: 16B-aligned,
  // banks 20q%32 distinct over q -> <=2-way = free)
  __shared__ __align__(16) short Plds[4][16 * 40];
  short* pw = &Plds[wave][0];

  const size_t qoff = ((size_t)bh * NPIX + qrow) * HD + g * 8;
  const s16x8 qh = *(const s16x8*)(Qhi + qoff);
  const s16x8 ql = *(const s16x8*)(Qlo + qoff);

  f32x4 O0 = {0.f, 0.f, 0.f, 0.f}, O1 = {0.f, 0.f, 0.f, 0.f};
  float m = -3.0e38f, l = 0.f;

  for (int kt = 0; kt < KPS / KT; ++kt) {
    const int j0 = split * KPS + kt * KT;
    // K A-frags: slice js: A[m=j0+js*16+q][k=d=g*8+jj]
    const size_t kbase = ((size_t)bh * NPIX + j0 + q) * HD + g * 8;
    s16x8 k0h = *(const s16x8*)(Khi + kbase);
    s16x8 k1h = *(const s16x8*)(Khi + kbase + 16 * HD);
    s16x8 k0l = *(const s16x8*)(Klo + kbase);
    s16x8 k1l = *(const s16x8*)(Klo + kbase + 16 * HD);
    // V A-frags: slice ds: A[m=d=ds*16+q][k=j=j0+g*8+jj]
    const size_t vbase = ((size_t)bh * HD + q) * NPIX + j0 + g * 8;
    s16x8 v0h = *(const s16x8*)(Vhi + vbase);
    s16x8 v1h = *(const s16x8*)(Vhi + vbase + 16 * NPIX);
    s16x8 v0l = *(const s16x8*)(Vlo + vbase);
    s16x8 v1l = *(const s16x8*)(Vlo + vbase + 16 * NPIX);

    f32x4 S0 = {0.f, 0.f, 0.f, 0.f}, S1 = {0.f, 0.f, 0.f, 0.f};
    S0 = __builtin_amdgcn_mfma_f32_16x16x32_bf16(k0h, qh, S0, 0, 0, 0);
    S0 = __builtin_amdgcn_mfma_f32_16x16x32_bf16(k0h, ql, S0, 0, 0, 0);
    S0 = __builtin_amdgcn_mfma_f32_16x16x32_bf16(k0l, qh, S0, 0, 0, 0);
    S1 = __builtin_amdgcn_mfma_f32_16x16x32_bf16(k1h, qh, S1, 0, 0, 0);
    S1 = __builtin_amdgcn_mfma_f32_16x16x32_bf16(k1h, ql, S1, 0, 0, 0);
    S1 = __builtin_amdgcn_mfma_f32_16x16x32_bf16(k1l, qh, S1, 0, 0, 0);

    // online softmax per q (col = lane&15): reduce over 8 regs + lanes xor16/32
    float tm = fmaxf(fmaxf(fmaxf(S0[0], S0[1]), fmaxf(S0[2], S0[3])),
                     fmaxf(fmaxf(S1[0], S1[1]), fmaxf(S1[2], S1[3])));
    tm = fmaxf(tm, __shfl_xor(tm, 16));
    tm = fmaxf(tm, __shfl_xor(tm, 32));
    const float nm = fmaxf(m, tm);
    const float alpha = exp2f(m - nm);
    m = nm;
    short pb[8];
    float ps = 0.f;
#pragma unroll
    for (int r = 0; r < 4; ++r) {
      float p0 = exp2f(S0[r] - nm);
      float p1 = exp2f(S1[r] - nm);
      pb[r] = f2bf(p0);
      pb[4 + r] = f2bf(p1);
      ps += bf2f(pb[r]) + bf2f(pb[4 + r]);   // sum the ROUNDED weights
    }
    ps += __shfl_xor(ps, 16);
    ps += __shfl_xor(ps, 32);
    l = l * alpha + ps;
#pragma unroll
    for (int r = 0; r < 4; ++r) { O0[r] *= alpha; O1[r] *= alpha; }

    // write P^T [q][j] (j = g*4+r for S0, 16+g*4+r for S1), read back B-frag
    uint2 w0, w1;
    w0.x = ((uint32_t)(uint16_t)pb[1] << 16) | (uint16_t)pb[0];
    w0.y = ((uint32_t)(uint16_t)pb[3] << 16) | (uint16_t)pb[2];
    w1.x = ((uint32_t)(uint16_t)pb[5] << 16) | (uint16_t)pb[4];
    w1.y = ((uint32_t)(uint16_t)pb[7] << 16) | (uint16_t)pb[6];
    *(uint2*)&pw[q * 40 + g * 4] = w0;
    *(uint2*)&pw[q * 40 + 16 + g * 4] = w1;
    s16x8 pf = *(const s16x8*)&pw[q * 40 + g * 8];   // B[k=j=g*8+jj][n=q]

    O0 = __builtin_amdgcn_mfma_f32_16x16x32_bf16(v0h, pf, O0, 0, 0, 0);
    O0 = __builtin_amdgcn_mfma_f32_16x16x32_bf16(v0l, pf, O0, 0, 0, 0);
    O1 = __builtin_amdgcn_mfma_f32_16x16x32_bf16(v1h, pf, O1, 0, 0, 0);
    O1 = __builtin_amdgcn_mfma_f32_16x16x32_bf16(v1l, pf, O1, 0, 0, 0);
  }

  const int row = bh * NPIX + qrow;
  float* po = part_o + ((size_t)row * NSPLIT + split) * HD;
  *(f32x4*)(po + g * 4) = O0;          // d = g*4 + r
  *(f32x4*)(po + 16 + g * 4) = O1;     // d = 16 + g*4 + r
  if (g == 0) {
    part_ml[(size_t)row * 2 * NSPLIT + split * 2] = m;
    part_ml[(size_t)row * 2 * NSPLIT + split * 2 + 1] = l;
  }
}

// ---------------------------------------------------------------------------
// Merge K-splits, write SCRAMBLED z: z[b][c=n/9][(n%9)*256 + head*32 + dd]
// ---------------------------------------------------------------------------
__global__ __launch_bounds__(256) void attn_merge(const float* __restrict__ part_o,
                                                  const float* __restrict__ part_ml,
                                                  float* __restrict__ z) {
  const int idx = blockIdx.x * 256 + threadIdx.x;
  const int n = idx % NPIX;
  const int bh = idx / NPIX;
  const int head = bh & 7, b = bh >> 3;
  float mm[NSPLIT], ll[NSPLIT];
  float m = -3.0e38f;
#pragma unroll
  for (int s = 0; s < NSPLIT; ++s) {
    mm[s] = part_ml[(size_t)idx * 2 * NSPLIT + s * 2];
    ll[s] = part_ml[(size_t)idx * 2 * NSPLIT + s * 2 + 1];
    m = fmaxf(m, mm[s]);
  }
  float w[NSPLIT];
  float L = 0.f;
#pragma unroll
  for (int s = 0; s < NSPLIT; ++s) {
    w[s] = exp2f(mm[s] - m);
    L += ll[s] * w[s];
  }
  const float inv = 1.f / L;
  float* zp = z + ((size_t)b * DIMC + n / 9) * NPIX + (n % 9) * DIMC + head * HD;
#pragma unroll
  for (int dd = 0; dd < HD; ++dd) {
    float acc = 0.f;
#pragma unroll
    for (int s = 0; s < NSPLIT; ++s)
      acc += part_o[((size_t)idx * NSPLIT + s) * HD + dd] * w[s];
    zp[dd] = acc * inv;
  }
}

// ---------------------------------------------------------------------------
extern "C" void kernel_launch(void* const* d_in, const int* in_sizes, int n_in,
                              void* d_out, int out_size, void* d_ws, size_t ws_size,
                              hipStream_t stream) {
  const float* x      = (const float*)d_in[0];
  const float* q_w    = (const float*)d_in[1];
  const float* q_b    = (const float*)d_in[2];
  const float* kv_w   = (const float*)d_in[3];
  const float* kv_b   = (const float*)d_in[4];
  const float* proj_w = (const float*)d_in[5];
  const float* proj_b = (const float*)d_in[6];
  float* out = (float*)d_out;

  // workspace carve-up with lifetime-based aliasing (~33 MB):
  //   [0]      xavg (4.7MB) ... later z (written after xavg dead)
  //   [4.7MB]  qb (4.7MB)   ... later part_ml
  //   [9.4MB]  kvb (9.4MB)  ... later part_o (kvb dead after converts)
  //   [18.9MB] Qhi/Qlo/Khi/Klo/Vhi/Vlo (6 x 2.36MB bf16)
  char* w = (char*)d_ws;
  float* xavg    = (float*)w;
  float* z       = xavg;                       // alias (xavg dead after kv gemm)
  float* qb      = (float*)(w + 4718592);
  float* part_ml = qb;                         // alias (qb dead after convert_t q)
  float* kvb     = (float*)(w + 2 * 4718592);
  float* part_o  = kvb;                        // alias (kvb dead after convert_v)
  short* Qhi = (short*)(w + 2 * 4718592 + 9437184);
  short* Qlo = Qhi + (size_t)16 * NPIX * HD;
  short* Khi = Qlo + (size_t)16 * NPIX * HD;
  short* Klo = Khi + (size_t)16 * NPIX * HD;
  short* Vhi = Klo + (size_t)16 * NPIX * HD;
  short* Vlo = Vhi + (size_t)16 * NPIX * HD;

  const float qscale = 0.17677669529663689f * 1.4426950408889634f; // d^-0.5 * log2(e)

  pool_kernel<<<BATCH * DIMC, 256, 0, stream>>>(x, xavg);
  gemm1x1<<<dim3(NPIX / BN, 256 / BO, BATCH), 256, 0, stream>>>(q_w, q_b, x, qb, 256, 256, NPIX);
  gemm1x1<<<dim3(NPIX / BN, 512 / BO, BATCH), 256, 0, stream>>>(kv_w, kv_b, xavg, kvb, 512, 256, NPIX);
  convert_t<<<dim3(36, 16), 256, 0, stream>>>(qb, Qhi, Qlo, 256, 0, qscale);
  convert_t<<<dim3(36, 16), 256, 0, stream>>>(kvb, Khi, Klo, 512, 0, 1.0f);
  convert_v<<<1152, 256, 0, stream>>>(kvb, Vhi, Vlo);
  attn_mfma<<<dim3(16 * 36, NSPLIT), 256, 0, stream>>>(Qhi, Qlo, Khi, Klo, Vhi, Vlo,
                                                       part_o, part_ml);
  attn_merge<<<BATCH * NH * NPIX / 256, 256, 0, stream>>>(part_o, part_ml, z);
  gemm1x1<<<dim3(NPIX / BN, 256 / BO, BATCH), 256, 0, stream>>>(proj_w, proj_b, z, out, 256, 256, NPIX);
}

// Round 3
// 245.288 us; speedup vs baseline: 3.3093x; 1.1831x over previous
//
#include <hip/hip_runtime.h>
#include <hip/hip_bf16.h>
#include <cstdint>

// Problem constants
#define DIMC  256
#define NH    8
#define HD    32
#define NPIX  2304       // 48*48
#define BATCH 2
#define NSPLIT 4
#define KPS   576        // keys per split (2304/4)
#define KT    32         // key tile per iteration

typedef short s16x8 __attribute__((ext_vector_type(8)));
typedef short s16x4 __attribute__((ext_vector_type(4)));
typedef float f32x4 __attribute__((ext_vector_type(4)));

__device__ inline short f2bf(float x) {            // RNE fp32 -> bf16 bits
  union { float f; uint32_t u; } a; a.f = x;
  uint32_t r = a.u + 0x7fffu + ((a.u >> 16) & 1u);
  return (short)(r >> 16);
}
__device__ inline float bf2f(short b) {
  union { uint32_t u; float f; } a; a.u = ((uint32_t)(uint16_t)b) << 16;
  return a.f;
}

// ---------------------------------------------------------------------------
// Pool: x_avg = (x + box3/9 + box5/25 + box7/49) / 4 (zero pad, include_pad)
// ---------------------------------------------------------------------------
__global__ __launch_bounds__(256) void pool_kernel(const float* __restrict__ x,
                                                   float* __restrict__ xavg) {
  const int plane = blockIdx.x;
  const float* xp = x + (size_t)plane * NPIX;
  __shared__ float sx[NPIX];
  __shared__ float h3[NPIX], h5[NPIX], h7[NPIX];
  const int t = threadIdx.x;
#pragma unroll
  for (int r = 0; r < 9; ++r) sx[r * 256 + t] = xp[r * 256 + t];
  __syncthreads();
#pragma unroll
  for (int r = 0; r < 9; ++r) {
    int p = r * 256 + t;
    int i = p / 48, j = p - i * 48;
    float a3 = 0.f, a5 = 0.f, a7 = 0.f;
#pragma unroll
    for (int dj = -3; dj <= 3; ++dj) {
      int jj = j + dj;
      if (jj < 0 || jj >= 48) continue;
      float v = sx[i * 48 + jj];
      a7 += v;
      if (dj >= -2 && dj <= 2) a5 += v;
      if (dj >= -1 && dj <= 1) a3 += v;
    }
    h3[p] = a3; h5[p] = a5; h7[p] = a7;
  }
  __syncthreads();
#pragma unroll
  for (int r = 0; r < 9; ++r) {
    int p = r * 256 + t;
    int i = p / 48, j = p - i * 48;
    float b3 = 0.f, b5 = 0.f, b7 = 0.f;
#pragma unroll
    for (int di = -3; di <= 3; ++di) {
      int ii = i + di;
      if (ii < 0 || ii >= 48) continue;
      int q = ii * 48 + j;
      b7 += h7[q];
      if (di >= -2 && di <= 2) b5 += h5[q];
      if (di >= -1 && di <= 1) b3 += h3[q];
    }
    xavg[(size_t)plane * NPIX + p] =
        0.25f * (sx[p] + b3 * (1.f / 9.f) + b5 * (1.f / 25.f) + b7 * (1.f / 49.f));
  }
}

// ---------------------------------------------------------------------------
// fp32 1x1-conv GEMM. BO=32 (o), BN=128 (n), BK=32; 256 threads, 2x8 out/thr.
// Smaller BO than R2 -> 2x blocks (288/576) so all CUs get work.
// ---------------------------------------------------------------------------
#define BO 32
#define BN 128
#define BK 32
__global__ __launch_bounds__(256) void gemm1x1(const float* __restrict__ W,
                                               const float* __restrict__ bias,
                                               const float* __restrict__ In,
                                               float* __restrict__ Out,
                                               int O, int C, int N) {
  const int b  = blockIdx.z;
  const int o0 = blockIdx.y * BO;
  const int n0 = blockIdx.x * BN;
  const float* Inb = In + (size_t)b * C * N;
  float* Outb = Out + (size_t)b * O * N;
  __shared__ __align__(16) float Wt[BK][BO];   // Wt[k][o]
  __shared__ __align__(16) float It[BK][BN];   // It[k][n]
  const int tid = threadIdx.x;
  const int to = tid >> 4;   // 0..15 -> 2 consecutive o
  const int tn = tid & 15;   // 0..15 -> 4 consecutive n (x2 at +64)
  float acc[2][8];
#pragma unroll
  for (int i = 0; i < 2; ++i)
#pragma unroll
    for (int j = 0; j < 8; ++j) acc[i][j] = 0.f;

  for (int c0 = 0; c0 < C; c0 += BK) {
    __syncthreads();
    {   // W tile transposed: o = tid/8 (0..31), k = (tid%8)*4
      int o = tid >> 3;
      int k = (tid & 7) * 4;
      const float* wp = W + (size_t)(o0 + o) * C + c0 + k;
      float4 w0 = *(const float4*)wp;
      Wt[k + 0][o] = w0.x; Wt[k + 1][o] = w0.y; Wt[k + 2][o] = w0.z; Wt[k + 3][o] = w0.w;
    }
    {   // In tile: k = tid/8, n = (tid%8)*16
      int k = tid >> 3;
      int n = (tid & 7) * 16;
      const float* ip = Inb + (size_t)(c0 + k) * N + n0 + n;
      float4* dst = (float4*)&It[k][n];
      const float4* src = (const float4*)ip;
      dst[0] = src[0]; dst[1] = src[1]; dst[2] = src[2]; dst[3] = src[3];
    }
    __syncthreads();
#pragma unroll
    for (int k = 0; k < BK; ++k) {
      float2 wv = *(const float2*)&Wt[k][to * 2];
      float4 i0 = *(const float4*)&It[k][tn * 4];
      float4 i1 = *(const float4*)&It[k][tn * 4 + 64];
      float wa[2] = {wv.x, wv.y};
      float ia[8] = {i0.x, i0.y, i0.z, i0.w, i1.x, i1.y, i1.z, i1.w};
#pragma unroll
      for (int i = 0; i < 2; ++i)
#pragma unroll
        for (int j = 0; j < 8; ++j) acc[i][j] += wa[i] * ia[j];
    }
  }
#pragma unroll
  for (int i = 0; i < 2; ++i) {
    int o = o0 + to * 2 + i;
    float bv = bias[o];
    float* op = Outb + (size_t)o * N + n0 + tn * 4;
    float4 r0 = {acc[i][0] + bv, acc[i][1] + bv, acc[i][2] + bv, acc[i][3] + bv};
    float4 r1 = {acc[i][4] + bv, acc[i][5] + bv, acc[i][6] + bv, acc[i][7] + bv};
    *(float4*)op = r0;
    *(float4*)(op + 64) = r1;
  }
}

// ---------------------------------------------------------------------------
// Transpose+split convert: src [b][srcC][N] channels ch0+h*32.. -> dst [bh][n][32]
// bf16 hi (+ optional lo), optional scale.
// ---------------------------------------------------------------------------
__global__ __launch_bounds__(256) void convert_t(const float* __restrict__ src,
                                                 short* __restrict__ dhi,
                                                 short* __restrict__ dlo,
                                                 int srcC, int ch0, float scale) {
  const int n0 = blockIdx.x * 64;
  const int bh = blockIdx.y;
  const int b = bh >> 3, h = bh & 7;
  const int t = threadIdx.x;
  __shared__ __align__(16) short Lhi[64 * 40], Llo[64 * 40];
  const bool wantlo = (dlo != nullptr);
  {
    const int d = t >> 3;
    const int nn = (t & 7) * 8;
    const float* sp = src + ((size_t)b * srcC + ch0 + h * HD + d) * NPIX + n0 + nn;
#pragma unroll
    for (int i = 0; i < 8; ++i) {
      float x = sp[i] * scale;
      short hi = f2bf(x);
      Lhi[(nn + i) * 40 + d] = hi;
      if (wantlo) Llo[(nn + i) * 40 + d] = f2bf(x - bf2f(hi));
    }
  }
  __syncthreads();
  {
    const int n = t >> 2;
    const int dg = (t & 3) * 8;
    s16x8 vh = *(const s16x8*)&Lhi[n * 40 + dg];
    size_t off = ((size_t)bh * NPIX + n0 + n) * HD + dg;
    *(s16x8*)(dhi + off) = vh;
    if (wantlo) {
      s16x8 vl = *(const s16x8*)&Llo[n * 40 + dg];
      *(s16x8*)(dlo + off) = vl;
    }
  }
}

// ---------------------------------------------------------------------------
// V convert (no transpose): kvb[b][256+c][n] -> Vhi [bh][d][n] bf16 (hi only)
// ---------------------------------------------------------------------------
__global__ __launch_bounds__(256) void convert_v(const float* __restrict__ kvb,
                                                 short* __restrict__ vhi) {
  const int idx = (blockIdx.x * 256 + threadIdx.x) * 4;   // over B*256*N
  const int b = idx / (DIMC * NPIX);
  const int r = idx - b * (DIMC * NPIX);
  const float* sp = kvb + ((size_t)b * 2 * DIMC + DIMC) * NPIX + r;
  float4 x = *(const float4*)sp;
  s16x4 hi;
  hi[0] = f2bf(x.x); hi[1] = f2bf(x.y); hi[2] = f2bf(x.z); hi[3] = f2bf(x.w);
  *(s16x4*)(vhi + idx) = hi;
}

// ---------------------------------------------------------------------------
// MFMA flash attention, transposed (S^T = K·Q^T, O^T = V^T·P^T).
// Block = 4 waves; wave w owns q-rows qblk*64 + w*16 .. +15, iterates KPS keys.
// Q hi+lo, K hi, V hi. P rounded RNA; l sums unrounded p (RNA ~unbiased).
// C-layout: col = lane&15 (= q), row = (lane>>4)*4 + reg.
// A-layout: m = lane&15, k = (lane>>4)*8 + j.  B-layout: n = lane&15, same k.
// ---------------------------------------------------------------------------
__global__ __launch_bounds__(256) void attn_mfma(
    const short* __restrict__ Qhi, const short* __restrict__ Qlo,   // [bh][n][32]
    const short* __restrict__ Khi,                                   // [bh][n][32]
    const short* __restrict__ Vhi,                                   // [bh][32][N]
    float* __restrict__ part_o,    // [row][NSPLIT][32]
    float* __restrict__ part_ml) { // [row][NSPLIT][2]
  const int qblk  = blockIdx.x % 36;
  const int bh    = blockIdx.x / 36;
  const int split = blockIdx.y;
  const int tid = threadIdx.x;
  const int wave = tid >> 6, lane = tid & 63;
  const int g = lane >> 4, q = lane & 15;
  const int qrow = qblk * 64 + wave * 16 + q;

  // per-wave private P^T scratch: [q][j] bf16, stride 40 shorts (proven R2)
  __shared__ __align__(16) short Plds[4][16 * 40];
  short* pw = &Plds[wave][0];

  const size_t qoff = ((size_t)bh * NPIX + qrow) * HD + g * 8;
  const s16x8 qh = *(const s16x8*)(Qhi + qoff);
  const s16x8 ql = *(const s16x8*)(Qlo + qoff);

  // loop-invariant lane offsets; iter-varying part is wave-uniform increments
  const short* kp = Khi + ((size_t)bh * NPIX + split * KPS + q) * HD + g * 8;
  const short* vp = Vhi + ((size_t)bh * HD + q) * NPIX + split * KPS + g * 8;

  f32x4 O0 = {0.f, 0.f, 0.f, 0.f}, O1 = {0.f, 0.f, 0.f, 0.f};
  float m = -3.0e38f, l = 0.f;   // l accumulated PER LANE; reduced at end

  for (int kt = 0; kt < KPS / KT; ++kt) {
    s16x8 k0h = *(const s16x8*)(kp);
    s16x8 k1h = *(const s16x8*)(kp + 16 * HD);
    s16x8 v0h = *(const s16x8*)(vp);
    s16x8 v1h = *(const s16x8*)(vp + 16 * NPIX);
    kp += KT * HD;
    vp += KT;

    f32x4 S0 = {0.f, 0.f, 0.f, 0.f}, S1 = {0.f, 0.f, 0.f, 0.f};
    S0 = __builtin_amdgcn_mfma_f32_16x16x32_bf16(k0h, qh, S0, 0, 0, 0);
    S0 = __builtin_amdgcn_mfma_f32_16x16x32_bf16(k0h, ql, S0, 0, 0, 0);
    S1 = __builtin_amdgcn_mfma_f32_16x16x32_bf16(k1h, qh, S1, 0, 0, 0);
    S1 = __builtin_amdgcn_mfma_f32_16x16x32_bf16(k1h, ql, S1, 0, 0, 0);

    // online softmax per q (col = lane&15)
    float tm = fmaxf(fmaxf(fmaxf(S0[0], S0[1]), fmaxf(S0[2], S0[3])),
                     fmaxf(fmaxf(S1[0], S1[1]), fmaxf(S1[2], S1[3])));
    tm = fmaxf(tm, __shfl_xor(tm, 16));
    tm = fmaxf(tm, __shfl_xor(tm, 32));
    const float nm = fmaxf(m, tm);
    const float alpha = exp2f(m - nm);
    m = nm;

    float p[8];
    float pl = 0.f;
#pragma unroll
    for (int r = 0; r < 4; ++r) {
      p[r]     = exp2f(S0[r] - nm);
      p[4 + r] = exp2f(S1[r] - nm);
      pl += p[r] + p[4 + r];
    }
    l = l * alpha + pl;
#pragma unroll
    for (int r = 0; r < 4; ++r) { O0[r] *= alpha; O1[r] *= alpha; }

    // pack P (RNA round: +0x8000 then truncate) -> bf16 pairs
    uint32_t a[8];
#pragma unroll
    for (int r = 0; r < 8; ++r) a[r] = __float_as_uint(p[r]) + 0x8000u;
    uint2 w0, w1;
    w0.x = (a[1] & 0xffff0000u) | (a[0] >> 16);
    w0.y = (a[3] & 0xffff0000u) | (a[2] >> 16);
    w1.x = (a[5] & 0xffff0000u) | (a[4] >> 16);
    w1.y = (a[7] & 0xffff0000u) | (a[6] >> 16);
    *(uint2*)&pw[q * 40 + g * 4] = w0;          // keys g*4 .. g*4+3
    *(uint2*)&pw[q * 40 + 16 + g * 4] = w1;     // keys 16+g*4 ..
    s16x8 pf = *(const s16x8*)&pw[q * 40 + g * 8];   // B[k=j=g*8+jj][n=q]

    O0 = __builtin_amdgcn_mfma_f32_16x16x32_bf16(v0h, pf, O0, 0, 0, 0);
    O1 = __builtin_amdgcn_mfma_f32_16x16x32_bf16(v1h, pf, O1, 0, 0, 0);
  }

  // final l reduction across the 4 lanes sharing q
  l += __shfl_xor(l, 16);
  l += __shfl_xor(l, 32);

  const int row = bh * NPIX + qrow;
  float* po = part_o + ((size_t)row * NSPLIT + split) * HD;
  *(f32x4*)(po + g * 4) = O0;          // d = g*4 + r
  *(f32x4*)(po + 16 + g * 4) = O1;     // d = 16 + g*4 + r
  if (g == 0) {
    part_ml[(size_t)row * 2 * NSPLIT + split * 2] = m;
    part_ml[(size_t)row * 2 * NSPLIT + split * 2 + 1] = l;
  }
}

// ---------------------------------------------------------------------------
// Merge K-splits, write SCRAMBLED z: z[b][c=n/9][(n%9)*256 + head*32 + dd]
// ---------------------------------------------------------------------------
__global__ __launch_bounds__(256) void attn_merge(const float* __restrict__ part_o,
                                                  const float* __restrict__ part_ml,
                                                  float* __restrict__ z) {
  const int idx = blockIdx.x * 256 + threadIdx.x;
  const int n = idx % NPIX;
  const int bh = idx / NPIX;
  const int head = bh & 7, b = bh >> 3;
  float mm[NSPLIT], ll[NSPLIT];
  float m = -3.0e38f;
#pragma unroll
  for (int s = 0; s < NSPLIT; ++s) {
    mm[s] = part_ml[(size_t)idx * 2 * NSPLIT + s * 2];
    ll[s] = part_ml[(size_t)idx * 2 * NSPLIT + s * 2 + 1];
    m = fmaxf(m, mm[s]);
  }
  float w[NSPLIT];
  float L = 0.f;
#pragma unroll
  for (int s = 0; s < NSPLIT; ++s) {
    w[s] = exp2f(mm[s] - m);
    L += ll[s] * w[s];
  }
  const float inv = 1.f / L;
  float* zp = z + ((size_t)b * DIMC + n / 9) * NPIX + (n % 9) * DIMC + head * HD;
#pragma unroll
  for (int dd = 0; dd < HD; ++dd) {
    float acc = 0.f;
#pragma unroll
    for (int s = 0; s < NSPLIT; ++s)
      acc += part_o[((size_t)idx * NSPLIT + s) * HD + dd] * w[s];
    zp[dd] = acc * inv;
  }
}

// ---------------------------------------------------------------------------
extern "C" void kernel_launch(void* const* d_in, const int* in_sizes, int n_in,
                              void* d_out, int out_size, void* d_ws, size_t ws_size,
                              hipStream_t stream) {
  const float* x      = (const float*)d_in[0];
  const float* q_w    = (const float*)d_in[1];
  const float* q_b    = (const float*)d_in[2];
  const float* kv_w   = (const float*)d_in[3];
  const float* kv_b   = (const float*)d_in[4];
  const float* proj_w = (const float*)d_in[5];
  const float* proj_b = (const float*)d_in[6];
  float* out = (float*)d_out;

  // workspace carve-up, lifetime-aliased (max 37.75 MB; ws >= 43.6 MB proven R1):
  //   @0        xavg 4.7MB            -> later z (merge output)
  //   @4.7MB    qb 4.7MB              -> later part_ml (1.2MB)
  //   @9.4MB    kvb 9.4MB             -> later part_o (18.9MB, spans to 28.3MB)
  //   @28.3MB   Qhi Qlo Khi Vhi (4 x 2.36MB)
  char* w = (char*)d_ws;
  float* xavg    = (float*)w;
  float* z       = xavg;
  float* qb      = (float*)(w + 4718592);
  float* part_ml = qb;
  float* kvb     = (float*)(w + 9437184);
  float* part_o  = kvb;
  short* Qhi = (short*)(w + 28311552);
  short* Qlo = Qhi + (size_t)16 * NPIX * HD;
  short* Khi = Qlo + (size_t)16 * NPIX * HD;
  short* Vhi = Khi + (size_t)16 * NPIX * HD;

  const float qscale = 0.17677669529663689f * 1.4426950408889634f; // d^-0.5 * log2(e)

  pool_kernel<<<BATCH * DIMC, 256, 0, stream>>>(x, xavg);
  gemm1x1<<<dim3(NPIX / BN, 256 / BO, BATCH), 256, 0, stream>>>(q_w, q_b, x, qb, 256, 256, NPIX);
  gemm1x1<<<dim3(NPIX / BN, 512 / BO, BATCH), 256, 0, stream>>>(kv_w, kv_b, xavg, kvb, 512, 256, NPIX);
  convert_t<<<dim3(36, 16), 256, 0, stream>>>(qb, Qhi, Qlo, 256, 0, qscale);
  convert_t<<<dim3(36, 16), 256, 0, stream>>>(kvb, Khi, nullptr, 512, 0, 1.0f);
  convert_v<<<1152, 256, 0, stream>>>(kvb, Vhi);
  attn_mfma<<<dim3(16 * 36, NSPLIT), 256, 0, stream>>>(Qhi, Qlo, Khi, Vhi, part_o, part_ml);
  attn_merge<<<BATCH * NH * NPIX / 256, 256, 0, stream>>>(part_o, part_ml, z);
  gemm1x1<<<dim3(NPIX / BN, 256 / BO, BATCH), 256, 0, stream>>>(proj_w, proj_b, z, out, 256, 256, NPIX);
}

// Round 4
// 212.937 us; speedup vs baseline: 3.8121x; 1.1519x over previous
//
#include <hip/hip_runtime.h>
#include <hip/hip_bf16.h>
#include <cstdint>

// Problem constants
#define DIMC  256
#define NH    8
#define HD    32
#define NPIX  2304       // 48*48
#define BATCH 2
#define NSPLIT 4
#define KPS   576        // keys per split
#define KT    32

typedef short s16x8 __attribute__((ext_vector_type(8)));
typedef float f32x4 __attribute__((ext_vector_type(4)));

// RNA (round-to-nearest-away) bf16 helpers: unbiased enough, 1 VALU each.
__device__ inline uint32_t rnau(float x) { return __float_as_uint(x) + 0x8000u; }
// pack two RNA'd dwords -> (bf16(l_) | bf16(h_)<<16)
__device__ inline uint32_t pk2(uint32_t l_, uint32_t h_) {
  return __builtin_amdgcn_perm(h_, l_, 0x07060302u);
}
__device__ inline float hif(uint32_t a) { return __uint_as_float(a & 0xffff0000u); }

// ---------------------------------------------------------------------------
// Pool: x_avg = (x + box3/9 + box5/25 + box7/49)/4, zero-pad, include_pad
// ---------------------------------------------------------------------------
__global__ __launch_bounds__(256) void pool_kernel(const float* __restrict__ x,
                                                   float* __restrict__ xavg) {
  const int plane = blockIdx.x;
  const float* xp = x + (size_t)plane * NPIX;
  __shared__ float sx[NPIX];
  __shared__ float h3[NPIX], h5[NPIX], h7[NPIX];
  const int t = threadIdx.x;
#pragma unroll
  for (int r = 0; r < 9; ++r) sx[r * 256 + t] = xp[r * 256 + t];
  __syncthreads();
#pragma unroll
  for (int r = 0; r < 9; ++r) {
    int p = r * 256 + t;
    int i = p / 48, j = p - i * 48;
    float a3 = 0.f, a5 = 0.f, a7 = 0.f;
#pragma unroll
    for (int dj = -3; dj <= 3; ++dj) {
      int jj = j + dj;
      if (jj < 0 || jj >= 48) continue;
      float v = sx[i * 48 + jj];
      a7 += v;
      if (dj >= -2 && dj <= 2) a5 += v;
      if (dj >= -1 && dj <= 1) a3 += v;
    }
    h3[p] = a3; h5[p] = a5; h7[p] = a7;
  }
  __syncthreads();
#pragma unroll
  for (int r = 0; r < 9; ++r) {
    int p = r * 256 + t;
    int i = p / 48, j = p - i * 48;
    float b3 = 0.f, b5 = 0.f, b7 = 0.f;
#pragma unroll
    for (int di = -3; di <= 3; ++di) {
      int ii = i + di;
      if (ii < 0 || ii >= 48) continue;
      int q = ii * 48 + j;
      b7 += h7[q];
      if (di >= -2 && di <= 2) b5 += h5[q];
      if (di >= -1 && di <= 1) b3 += h3[q];
    }
    xavg[(size_t)plane * NPIX + p] =
        0.25f * (sx[p] + b3 * (1.f / 9.f) + b5 * (1.f / 25.f) + b7 * (1.f / 49.f));
  }
}

// ---------------------------------------------------------------------------
// Transpose-convert: src fp32 [B][256][NPIX] -> dhi/dlo bf16 [B][NPIX][256]
// ---------------------------------------------------------------------------
__global__ __launch_bounds__(256) void tconv(const float* __restrict__ src,
                                             short* __restrict__ dhi,
                                             short* __restrict__ dlo) {
  const int n0 = blockIdx.x * 64, c0 = blockIdx.y * 64, b = blockIdx.z;
  const int t = threadIdx.x;
  __shared__ __align__(16) float T[64][68];
  {
    const int c = t >> 2, n4 = (t & 3) * 16;
    const float* sp = src + ((size_t)b * DIMC + c0 + c) * NPIX + n0 + n4;
#pragma unroll
    for (int i2 = 0; i2 < 4; ++i2)
      *(f32x4*)&T[c][n4 + i2 * 4] = *(const f32x4*)(sp + i2 * 4);
  }
  __syncthreads();
  {
    const int n = t >> 2, c4 = (t & 3) * 16;
    float v[16];
#pragma unroll
    for (int i = 0; i < 16; ++i) v[i] = T[c4 + i][n];
    uint32_t a[16];
#pragma unroll
    for (int i = 0; i < 16; ++i) a[i] = rnau(v[i]);
    union { s16x8 s; uint32_t u[4]; } H0, H1, L0, L1;
#pragma unroll
    for (int j = 0; j < 4; ++j) {
      H0.u[j] = pk2(a[2 * j], a[2 * j + 1]);
      H1.u[j] = pk2(a[8 + 2 * j], a[8 + 2 * j + 1]);
    }
    uint32_t al[16];
#pragma unroll
    for (int i = 0; i < 16; ++i) al[i] = rnau(v[i] - hif(a[i]));
#pragma unroll
    for (int j = 0; j < 4; ++j) {
      L0.u[j] = pk2(al[2 * j], al[2 * j + 1]);
      L1.u[j] = pk2(al[8 + 2 * j], al[8 + 2 * j + 1]);
    }
    const size_t off = ((size_t)b * NPIX + n0 + n) * DIMC + c0 + c4;
    *(s16x8*)(dhi + off) = H0.s; *(s16x8*)(dhi + off + 8) = H1.s;
    *(s16x8*)(dlo + off) = L0.s; *(s16x8*)(dlo + off + 8) = L1.s;
  }
}

// ---------------------------------------------------------------------------
// Weight convert (no transpose): q_w|kv_w|proj_w fp32 -> concat bf16 hi/lo
// layout: q at [0,65536), kv at [65536,196608), proj at [196608,262144)
// ---------------------------------------------------------------------------
__global__ __launch_bounds__(256) void wconv(const float* __restrict__ qw,
                                             const float* __restrict__ kvw,
                                             const float* __restrict__ pw_,
                                             short* __restrict__ Wth,
                                             short* __restrict__ Wtl) {
  const int idx = (blockIdx.x * 256 + threadIdx.x) * 8;
  const float* s;
  int off;
  if (idx < 65536)       { s = qw;  off = idx; }
  else if (idx < 196608) { s = kvw; off = idx - 65536; }
  else                   { s = pw_; off = idx - 196608; }
  f32x4 x0 = *(const f32x4*)(s + off);
  f32x4 x1 = *(const f32x4*)(s + off + 4);
  float v[8] = {x0[0], x0[1], x0[2], x0[3], x1[0], x1[1], x1[2], x1[3]};
  uint32_t a[8], al[8];
#pragma unroll
  for (int i = 0; i < 8; ++i) a[i] = rnau(v[i]);
#pragma unroll
  for (int i = 0; i < 8; ++i) al[i] = rnau(v[i] - hif(a[i]));
  union { s16x8 s; uint32_t u[4]; } H, L;
#pragma unroll
  for (int j = 0; j < 4; ++j) {
    H.u[j] = pk2(a[2 * j], a[2 * j + 1]);
    L.u[j] = pk2(al[2 * j], al[2 * j + 1]);
  }
  *(s16x8*)(Wth + idx) = H.s;
  *(s16x8*)(Wtl + idx) = L.s;
}

// ---------------------------------------------------------------------------
// MFMA 1x1-conv GEMM: Out[o][n] = sum_c W[o][c]*In[n][c] (+bias), hi/lo bf16,
// 3 MFMAs (hh + h*lo + lo*h). Block = 2 waves, tile 32o x 64n, K-step 32.
// Epilogue via LDS transpose:
//   mode 0 (PROJ): fp32 out[b][o][n] + bias
//   mode 1 (Q):    (C+bias)*scale -> Qhi/Qlo [bh][n][32]
//   mode 2 (KV):   o<256 -> Khi [bh][n][32]; o>=256 -> Vhi [bh][d][n]
// ---------------------------------------------------------------------------
__global__ __launch_bounds__(128) void gemm_mfma(
    const short* __restrict__ Wh, const short* __restrict__ Wl,
    const float* __restrict__ bias,
    const short* __restrict__ Inh, const short* __restrict__ Inl,
    float* __restrict__ outf, short* __restrict__ d1, short* __restrict__ d2,
    int mode, float scale) {
  const int n0 = blockIdx.x * 64;
  const int o0 = blockIdx.y * 32;
  const int b  = blockIdx.z;
  const int tid = threadIdx.x;
  const int wave = tid >> 6, lane = tid & 63;
  const int g = lane >> 4, q = lane & 15;

  const short* wph = Wh + ((o0 + wave * 16 + q) * DIMC + g * 8);
  const short* wpl = Wl + ((o0 + wave * 16 + q) * DIMC + g * 8);
  const short* iph = Inh + ((size_t)(b * NPIX + n0 + q) * DIMC + g * 8);
  const short* ipl = Inl + ((size_t)(b * NPIX + n0 + q) * DIMC + g * 8);

  f32x4 acc[4] = {{0,0,0,0},{0,0,0,0},{0,0,0,0},{0,0,0,0}};
#pragma unroll
  for (int c0 = 0; c0 < DIMC; c0 += 32) {
    s16x8 ah = *(const s16x8*)(wph + c0);
    s16x8 al = *(const s16x8*)(wpl + c0);
#pragma unroll
    for (int st = 0; st < 4; ++st) {
      s16x8 bh_ = *(const s16x8*)(iph + (size_t)st * 16 * DIMC + c0);
      s16x8 bl_ = *(const s16x8*)(ipl + (size_t)st * 16 * DIMC + c0);
      acc[st] = __builtin_amdgcn_mfma_f32_16x16x32_bf16(ah, bh_, acc[st], 0, 0, 0);
      acc[st] = __builtin_amdgcn_mfma_f32_16x16x32_bf16(ah, bl_, acc[st], 0, 0, 0);
      acc[st] = __builtin_amdgcn_mfma_f32_16x16x32_bf16(al, bh_, acc[st], 0, 0, 0);
    }
  }

  // stage C tiles: Cl[o_local][n_local]  (C-layout: col=lane&15=n, row=g*4+r=o)
  __shared__ __align__(16) float Cl[32][68];
#pragma unroll
  for (int st = 0; st < 4; ++st)
#pragma unroll
    for (int r = 0; r < 4; ++r)
      Cl[wave * 16 + g * 4 + r][st * 16 + q] = acc[st][r];
  __syncthreads();

  if (mode == 0) {
    const int o = tid >> 2, nc = (tid & 3) * 16;
    const float bv = bias[o0 + o];
    float* op = outf + ((size_t)b * DIMC + o0 + o) * NPIX + n0 + nc;
#pragma unroll
    for (int i2 = 0; i2 < 4; ++i2) {
      f32x4 v = *(const f32x4*)&Cl[o][nc + i2 * 4];
      v[0] += bv; v[1] += bv; v[2] += bv; v[3] += bv;
      *(f32x4*)(op + i2 * 4) = v;
    }
  } else if (mode == 1 || o0 < 256) {
    // Q (hi+lo, scaled) or K (hi only): dst layout [bh][n][32]
    const int n = tid >> 1, oq = tid & 1;
    const int h = o0 >> 5;
    const float* bp = bias + o0 + oq * 16;
    float v[16];
#pragma unroll
    for (int i = 0; i < 16; ++i) v[i] = (Cl[oq * 16 + i][n] + bp[i]) * scale;
    uint32_t a[16];
#pragma unroll
    for (int i = 0; i < 16; ++i) a[i] = rnau(v[i]);
    union { s16x8 s; uint32_t u[4]; } H0, H1;
#pragma unroll
    for (int j = 0; j < 4; ++j) {
      H0.u[j] = pk2(a[2 * j], a[2 * j + 1]);
      H1.u[j] = pk2(a[8 + 2 * j], a[8 + 2 * j + 1]);
    }
    const size_t off = ((size_t)((b * 8 + h) * NPIX + n0 + n)) * HD + oq * 16;
    *(s16x8*)(d1 + off) = H0.s; *(s16x8*)(d1 + off + 8) = H1.s;
    if (mode == 1) {
      uint32_t al[16];
#pragma unroll
      for (int i = 0; i < 16; ++i) al[i] = rnau(v[i] - hif(a[i]));
      union { s16x8 s; uint32_t u[4]; } L0, L1;
#pragma unroll
      for (int j = 0; j < 4; ++j) {
        L0.u[j] = pk2(al[2 * j], al[2 * j + 1]);
        L1.u[j] = pk2(al[8 + 2 * j], al[8 + 2 * j + 1]);
      }
      *(s16x8*)(d2 + off) = L0.s; *(s16x8*)(d2 + off + 8) = L1.s;
    }
  } else {
    // V (hi only): dst [bh][d][n], d = o0-256+o (o0 mult of 32 -> h const)
    const int o = tid >> 2, nc = (tid & 3) * 16;
    const int h = (o0 - 256) >> 5;
    const float bv = bias[o0 + o];
    float v[16];
#pragma unroll
    for (int i2 = 0; i2 < 4; ++i2) {
      f32x4 t4 = *(const f32x4*)&Cl[o][nc + i2 * 4];
      v[i2 * 4 + 0] = t4[0] + bv; v[i2 * 4 + 1] = t4[1] + bv;
      v[i2 * 4 + 2] = t4[2] + bv; v[i2 * 4 + 3] = t4[3] + bv;
    }
    uint32_t a[16];
#pragma unroll
    for (int i = 0; i < 16; ++i) a[i] = rnau(v[i]);
    union { s16x8 s; uint32_t u[4]; } H0, H1;
#pragma unroll
    for (int j = 0; j < 4; ++j) {
      H0.u[j] = pk2(a[2 * j], a[2 * j + 1]);
      H1.u[j] = pk2(a[8 + 2 * j], a[8 + 2 * j + 1]);
    }
    const size_t off = ((size_t)((b * 8 + h) * HD + o)) * NPIX + n0 + nc;
    *(s16x8*)(d2 + off) = H0.s; *(s16x8*)(d2 + off + 8) = H1.s;
  }
}

// ---------------------------------------------------------------------------
// MFMA flash attention, no-max softmax (scores provably |S|<~26 in log2),
// lag-1 PV pipeline. Q hi+lo (pre-scaled by SCALE*log2e), K hi, V hi.
// ---------------------------------------------------------------------------
__global__ __launch_bounds__(256) void attn_mfma(
    const short* __restrict__ Qhi, const short* __restrict__ Qlo,  // [bh][n][32]
    const short* __restrict__ Khi,                                  // [bh][n][32]
    const short* __restrict__ Vhi,                                  // [bh][32][N]
    float* __restrict__ part_o,   // [row][NSPLIT][32]
    float* __restrict__ part_l) { // [row][NSPLIT]
  const int qblk  = blockIdx.x % 36;
  const int bh    = blockIdx.x / 36;
  const int split = blockIdx.y;
  const int tid = threadIdx.x;
  const int wave = tid >> 6, lane = tid & 63;
  const int g = lane >> 4, q = lane & 15;
  const int qrow = qblk * 64 + wave * 16 + q;

  __shared__ __align__(16) short Plds[4][16 * 40];
  short* pw = &Plds[wave][0];

  const size_t qoff = ((size_t)bh * NPIX + qrow) * HD + g * 8;
  const s16x8 qh = *(const s16x8*)(Qhi + qoff);
  const s16x8 ql = *(const s16x8*)(Qlo + qoff);

  const short* kp = Khi + ((size_t)bh * NPIX + split * KPS + q) * HD + g * 8;
  const short* vp = Vhi + ((size_t)bh * HD + q) * NPIX + split * KPS + g * 8;

  f32x4 O0 = {0,0,0,0}, O1 = {0,0,0,0};
  float l = 0.f;
  s16x8 kb[2][2], vb[2][2], pf, vprev0, vprev1;

  kb[0][0] = *(const s16x8*)(kp);
  kb[0][1] = *(const s16x8*)(kp + 16 * HD);
  vb[0][0] = *(const s16x8*)(vp);
  vb[0][1] = *(const s16x8*)(vp + 16 * NPIX);

#pragma unroll
  for (int t = 0; t < 18; ++t) {
    const int cur = t & 1, nxt = cur ^ 1;
    if (t < 17) {
      const short* kpn = kp + (t + 1) * (KT * HD);
      const short* vpn = vp + (t + 1) * KT;
      kb[nxt][0] = *(const s16x8*)(kpn);
      kb[nxt][1] = *(const s16x8*)(kpn + 16 * HD);
      vb[nxt][0] = *(const s16x8*)(vpn);
      vb[nxt][1] = *(const s16x8*)(vpn + 16 * NPIX);
    }
    f32x4 S0 = {0,0,0,0}, S1 = {0,0,0,0};
    S0 = __builtin_amdgcn_mfma_f32_16x16x32_bf16(kb[cur][0], qh, S0, 0, 0, 0);
    S0 = __builtin_amdgcn_mfma_f32_16x16x32_bf16(kb[cur][0], ql, S0, 0, 0, 0);
    S1 = __builtin_amdgcn_mfma_f32_16x16x32_bf16(kb[cur][1], qh, S1, 0, 0, 0);
    S1 = __builtin_amdgcn_mfma_f32_16x16x32_bf16(kb[cur][1], ql, S1, 0, 0, 0);
    if (t > 0) {   // PV for tile t-1 (pf read issued last iter -> latency hidden)
      O0 = __builtin_amdgcn_mfma_f32_16x16x32_bf16(vprev0, pf, O0, 0, 0, 0);
      O1 = __builtin_amdgcn_mfma_f32_16x16x32_bf16(vprev1, pf, O1, 0, 0, 0);
    }
    float p[8];
#pragma unroll
    for (int r = 0; r < 4; ++r) { p[r] = exp2f(S0[r]); p[4 + r] = exp2f(S1[r]); }
    l += ((p[0] + p[1]) + (p[2] + p[3])) + ((p[4] + p[5]) + (p[6] + p[7]));
    uint32_t a[8];
#pragma unroll
    for (int r = 0; r < 8; ++r) a[r] = rnau(p[r]);
    uint2 w0, w1;
    w0.x = pk2(a[0], a[1]); w0.y = pk2(a[2], a[3]);
    w1.x = pk2(a[4], a[5]); w1.y = pk2(a[6], a[7]);
    *(uint2*)&pw[q * 40 + g * 4] = w0;          // keys g*4..g*4+3
    *(uint2*)&pw[q * 40 + 16 + g * 4] = w1;     // keys 16+g*4..
    vprev0 = vb[cur][0]; vprev1 = vb[cur][1];
    pf = *(const s16x8*)&pw[q * 40 + g * 8];    // consumed next iter
  }
  O0 = __builtin_amdgcn_mfma_f32_16x16x32_bf16(vprev0, pf, O0, 0, 0, 0);
  O1 = __builtin_amdgcn_mfma_f32_16x16x32_bf16(vprev1, pf, O1, 0, 0, 0);

  l += __shfl_xor(l, 16);
  l += __shfl_xor(l, 32);

  const int row = bh * NPIX + qrow;
  float* po = part_o + ((size_t)row * NSPLIT + split) * HD;
  *(f32x4*)(po + g * 4) = O0;
  *(f32x4*)(po + 16 + g * 4) = O1;
  if (g == 0) part_l[(size_t)row * NSPLIT + split] = l;
}

// ---------------------------------------------------------------------------
// Merge splits (plain sums; no max needed) and emit SCRAMBLED z_t hi/lo
// [b][p][256]: p=(n%9)*256+head*32+dd, c=n/9. 288 threads = 288 n-rows.
// ---------------------------------------------------------------------------
__global__ __launch_bounds__(288) void attn_merge(const float* __restrict__ part_o,
                                                  const float* __restrict__ part_l,
                                                  short* __restrict__ zh,
                                                  short* __restrict__ zl) {
  const int blk = blockIdx.x;          // 128 = 16 bh * 8
  const int bh = blk >> 3;
  const int n0 = (blk & 7) * 288;
  const int head = bh & 7, b = bh >> 3;
  const int t = threadIdx.x;
  __shared__ __align__(16) float T[288][36];
  {
    const int idx = bh * NPIX + n0 + t;
    f32x4 lv = *(const f32x4*)(part_l + (size_t)idx * NSPLIT);
    const float inv = 1.f / (lv[0] + lv[1] + lv[2] + lv[3]);
    const float* po = part_o + (size_t)idx * (NSPLIT * HD);
#pragma unroll
    for (int u = 0; u < 8; ++u) {
      f32x4 s0 = *(const f32x4*)(po + 0 * HD + u * 4);
      f32x4 s1 = *(const f32x4*)(po + 1 * HD + u * 4);
      f32x4 s2 = *(const f32x4*)(po + 2 * HD + u * 4);
      f32x4 s3 = *(const f32x4*)(po + 3 * HD + u * 4);
      f32x4 v = (s0 + s1) + (s2 + s3);
      v[0] *= inv; v[1] *= inv; v[2] *= inv; v[3] *= inv;
      *(f32x4*)&T[t][u * 4] = v;
    }
  }
  __syncthreads();
  {
    const int r9 = t / 32, dd = t & 31;
    const int p = r9 * 256 + head * HD + dd;
    const int c0 = n0 / 9;
    float v[32];
#pragma unroll
    for (int j = 0; j < 32; ++j) v[j] = T[9 * j + r9][dd];
    uint32_t a[32], al[32];
#pragma unroll
    for (int j = 0; j < 32; ++j) a[j] = rnau(v[j]);
#pragma unroll
    for (int j = 0; j < 32; ++j) al[j] = rnau(v[j] - hif(a[j]));
    const size_t off = ((size_t)b * NPIX + p) * DIMC + c0;
#pragma unroll
    for (int c8 = 0; c8 < 4; ++c8) {
      union { s16x8 s; uint32_t u[4]; } H, L;
#pragma unroll
      for (int j = 0; j < 4; ++j) {
        H.u[j] = pk2(a[c8 * 8 + 2 * j], a[c8 * 8 + 2 * j + 1]);
        L.u[j] = pk2(al[c8 * 8 + 2 * j], al[c8 * 8 + 2 * j + 1]);
      }
      *(s16x8*)(zh + off + c8 * 8) = H.s;
      *(s16x8*)(zl + off + c8 * 8) = L.s;
    }
  }
}

// ---------------------------------------------------------------------------
extern "C" void kernel_launch(void* const* d_in, const int* in_sizes, int n_in,
                              void* d_out, int out_size, void* d_ws, size_t ws_size,
                              hipStream_t stream) {
  const float* x      = (const float*)d_in[0];
  const float* q_w    = (const float*)d_in[1];
  const float* q_b    = (const float*)d_in[2];
  const float* kv_w   = (const float*)d_in[3];
  const float* kv_b   = (const float*)d_in[4];
  const float* proj_w = (const float*)d_in[5];
  const float* proj_b = (const float*)d_in[6];
  float* out = (float*)d_out;

  // Workspace (~34.7 MB; <= 43.6MB proven available in R1).
  // Region [0, 18.87MB): xavg/x_t/xavg_t during prologue, then part_o (attn).
  char* w = (char*)d_ws;
  float* xavg = (float*)w;                       // 4,718,592 B
  short* Xh   = (short*)(w + 4718592);           // 2,359,296 B each
  short* Xl   = (short*)(w + 7077888);
  short* Ah   = (short*)(w + 9437184);
  short* Al   = (short*)(w + 11796480);
  float* part_o = (float*)w;                     // 18,874,368 B (aliases above)
  short* Wth  = (short*)(w + 18874368);          // 524,288 B
  short* Wtl  = (short*)(w + 19398656);          // 524,288 B
  short* Qhi  = (short*)(w + 19922944);          // 2,359,296 B
  short* Qlo  = (short*)(w + 22282240);
  short* Khi  = (short*)(w + 24641536);
  short* Vhi  = (short*)(w + 27000832);
  float* part_l = (float*)(w + 29360128);        // 589,824 B
  short* Zh   = (short*)(w + 29949952);
  short* Zl   = (short*)(w + 32309248);          // ends 34,668,544

  const float qscale = 0.17677669529663689f * 1.4426950408889634f; // d^-0.5*log2(e)

  pool_kernel<<<BATCH * DIMC, 256, 0, stream>>>(x, xavg);
  tconv<<<dim3(36, 4, 2), 256, 0, stream>>>(x, Xh, Xl);
  tconv<<<dim3(36, 4, 2), 256, 0, stream>>>(xavg, Ah, Al);
  wconv<<<128, 256, 0, stream>>>(q_w, kv_w, proj_w, Wth, Wtl);
  gemm_mfma<<<dim3(36, 8, 2), 128, 0, stream>>>(Wth, Wtl, q_b, Xh, Xl,
                                                nullptr, Qhi, Qlo, 1, qscale);
  gemm_mfma<<<dim3(36, 16, 2), 128, 0, stream>>>(Wth + 65536, Wtl + 65536, kv_b,
                                                 Ah, Al, nullptr, Khi, Vhi, 2, 1.0f);
  attn_mfma<<<dim3(16 * 36, NSPLIT), 256, 0, stream>>>(Qhi, Qlo, Khi, Vhi,
                                                       part_o, part_l);
  attn_merge<<<128, 288, 0, stream>>>(part_o, part_l, Zh, Zl);
  gemm_mfma<<<dim3(36, 8, 2), 128, 0, stream>>>(Wth + 196608, Wtl + 196608, proj_b,
                                                Zh, Zl, out, nullptr, nullptr, 0, 1.0f);
}

// Round 5
// 182.620 us; speedup vs baseline: 4.4450x; 1.1660x over previous
//
#include <hip/hip_runtime.h>
#include <hip/hip_bf16.h>
#include <cstdint>

// Problem constants
#define DIMC  256
#define NH    8
#define HD    32
#define NPIX  2304       // 48*48
#define BATCH 2
#define NSPLIT 4
#define KPS   576        // keys per split
#define KT    32

typedef short s16x8 __attribute__((ext_vector_type(8)));
typedef float f32x4 __attribute__((ext_vector_type(4)));

// RNA (round-to-nearest-away) bf16 helpers: 1 VALU each.
__device__ inline uint32_t rnau(float x) { return __float_as_uint(x) + 0x8000u; }
__device__ inline uint32_t pk2(uint32_t l_, uint32_t h_) {
  return __builtin_amdgcn_perm(h_, l_, 0x07060302u);
}
__device__ inline float hif(uint32_t a) { return __uint_as_float(a & 0xffff0000u); }

// ---------------------------------------------------------------------------
// Pool: x_avg = (x + box3/9 + box5/25 + box7/49)/4, zero-pad, include_pad
// ---------------------------------------------------------------------------
__global__ __launch_bounds__(256) void pool_kernel(const float* __restrict__ x,
                                                   float* __restrict__ xavg) {
  const int plane = blockIdx.x;
  const float* xp = x + (size_t)plane * NPIX;
  __shared__ float sx[NPIX];
  __shared__ float h3[NPIX], h5[NPIX], h7[NPIX];
  const int t = threadIdx.x;
#pragma unroll
  for (int r = 0; r < 9; ++r) sx[r * 256 + t] = xp[r * 256 + t];
  __syncthreads();
#pragma unroll
  for (int r = 0; r < 9; ++r) {
    int p = r * 256 + t;
    int i = p / 48, j = p - i * 48;
    float a3 = 0.f, a5 = 0.f, a7 = 0.f;
#pragma unroll
    for (int dj = -3; dj <= 3; ++dj) {
      int jj = j + dj;
      if (jj < 0 || jj >= 48) continue;
      float v = sx[i * 48 + jj];
      a7 += v;
      if (dj >= -2 && dj <= 2) a5 += v;
      if (dj >= -1 && dj <= 1) a3 += v;
    }
    h3[p] = a3; h5[p] = a5; h7[p] = a7;
  }
  __syncthreads();
#pragma unroll
  for (int r = 0; r < 9; ++r) {
    int p = r * 256 + t;
    int i = p / 48, j = p - i * 48;
    float b3 = 0.f, b5 = 0.f, b7 = 0.f;
#pragma unroll
    for (int di = -3; di <= 3; ++di) {
      int ii = i + di;
      if (ii < 0 || ii >= 48) continue;
      int q = ii * 48 + j;
      b7 += h7[q];
      if (di >= -2 && di <= 2) b5 += h5[q];
      if (di >= -1 && di <= 1) b3 += h3[q];
    }
    xavg[(size_t)plane * NPIX + p] =
        0.25f * (sx[p] + b3 * (1.f / 9.f) + b5 * (1.f / 25.f) + b7 * (1.f / 49.f));
  }
}

// ---------------------------------------------------------------------------
// Fused converts: blocks 0..287 tconv(x), 288..575 tconv(xavg), 576..703 wconv
// tconv: fp32 [B][256][NPIX] -> hi/lo bf16 [B][NPIX][256]
// wconv: q_w|kv_w|proj_w fp32 -> concat bf16 hi/lo (q@0, kv@65536, proj@196608)
// ---------------------------------------------------------------------------
__global__ __launch_bounds__(256) void conv_all(
    const float* __restrict__ x, const float* __restrict__ xavg,
    const float* __restrict__ qw, const float* __restrict__ kvw,
    const float* __restrict__ pw_,
    short* __restrict__ Xh, short* __restrict__ Xl,
    short* __restrict__ Ah, short* __restrict__ Al,
    short* __restrict__ Wth, short* __restrict__ Wtl) {
  const int bx = blockIdx.x;
  const int t = threadIdx.x;
  if (bx < 576) {
    const float* src = (bx < 288) ? x : xavg;
    short* dhi = (bx < 288) ? Xh : Ah;
    short* dlo = (bx < 288) ? Xl : Al;
    const int bb = (bx < 288) ? bx : bx - 288;
    const int n0 = (bb % 36) * 64, c0 = ((bb / 36) & 3) * 64, b = bb / 144;
    __shared__ __align__(16) float T[64][68];
    {
      const int c = t >> 2, n4 = (t & 3) * 16;
      const float* sp = src + ((size_t)b * DIMC + c0 + c) * NPIX + n0 + n4;
#pragma unroll
      for (int i2 = 0; i2 < 4; ++i2)
        *(f32x4*)&T[c][n4 + i2 * 4] = *(const f32x4*)(sp + i2 * 4);
    }
    __syncthreads();
    {
      const int n = t >> 2, c4 = (t & 3) * 16;
      float v[16];
#pragma unroll
      for (int i = 0; i < 16; ++i) v[i] = T[c4 + i][n];
      uint32_t a[16], al[16];
#pragma unroll
      for (int i = 0; i < 16; ++i) a[i] = rnau(v[i]);
#pragma unroll
      for (int i = 0; i < 16; ++i) al[i] = rnau(v[i] - hif(a[i]));
      union { s16x8 s; uint32_t u[4]; } H0, H1, L0, L1;
#pragma unroll
      for (int j = 0; j < 4; ++j) {
        H0.u[j] = pk2(a[2 * j], a[2 * j + 1]);
        H1.u[j] = pk2(a[8 + 2 * j], a[8 + 2 * j + 1]);
        L0.u[j] = pk2(al[2 * j], al[2 * j + 1]);
        L1.u[j] = pk2(al[8 + 2 * j], al[8 + 2 * j + 1]);
      }
      const size_t off = ((size_t)b * NPIX + n0 + n) * DIMC + c0 + c4;
      *(s16x8*)(dhi + off) = H0.s; *(s16x8*)(dhi + off + 8) = H1.s;
      *(s16x8*)(dlo + off) = L0.s; *(s16x8*)(dlo + off + 8) = L1.s;
    }
  } else {
    const int idx = ((bx - 576) * 256 + t) * 8;
    const float* s;
    int off;
    if (idx < 65536)       { s = qw;  off = idx; }
    else if (idx < 196608) { s = kvw; off = idx - 65536; }
    else                   { s = pw_; off = idx - 196608; }
    f32x4 x0 = *(const f32x4*)(s + off);
    f32x4 x1 = *(const f32x4*)(s + off + 4);
    float v[8] = {x0[0], x0[1], x0[2], x0[3], x1[0], x1[1], x1[2], x1[3]};
    uint32_t a[8], al[8];
#pragma unroll
    for (int i = 0; i < 8; ++i) a[i] = rnau(v[i]);
#pragma unroll
    for (int i = 0; i < 8; ++i) al[i] = rnau(v[i] - hif(a[i]));
    union { s16x8 s; uint32_t u[4]; } H, L;
#pragma unroll
    for (int j = 0; j < 4; ++j) {
      H.u[j] = pk2(a[2 * j], a[2 * j + 1]);
      L.u[j] = pk2(al[2 * j], al[2 * j + 1]);
    }
    *(s16x8*)(Wth + idx) = H.s;
    *(s16x8*)(Wtl + idx) = L.s;
  }
}

// ---------------------------------------------------------------------------
// GEMM body (device): Out[o][n] = sum_c W[o][c]*In[n][c] (+bias), hi/lo bf16,
// 3 MFMAs. 2 waves, tile 32o x 64n. Epilogue:
//   mode 0 (PROJ): fp32 out[b][o][n] + bias
//   mode 2: o0<256 -> (C+bias)*scale hi-only [bh][n][32] into d1 (Q or K);
//           o0>=256 -> V hi-only [bh][d][n] into d2
// ---------------------------------------------------------------------------
__device__ __forceinline__ void gemm_body(
    const short* __restrict__ Wh, const short* __restrict__ Wl,
    const float* __restrict__ bias,
    const short* __restrict__ Inh, const short* __restrict__ Inl,
    float* __restrict__ outf, short* __restrict__ d1, short* __restrict__ d2,
    int mode, float scale, int n0, int o0, int b, float (*Cl)[68]) {
  const int tid = threadIdx.x;
  const int wave = tid >> 6, lane = tid & 63;
  const int g = lane >> 4, q = lane & 15;

  const short* wph = Wh + ((o0 + wave * 16 + q) * DIMC + g * 8);
  const short* wpl = Wl + ((o0 + wave * 16 + q) * DIMC + g * 8);
  const short* iph = Inh + ((size_t)(b * NPIX + n0 + q) * DIMC + g * 8);
  const short* ipl = Inl + ((size_t)(b * NPIX + n0 + q) * DIMC + g * 8);

  f32x4 acc[4] = {{0,0,0,0},{0,0,0,0},{0,0,0,0},{0,0,0,0}};
#pragma unroll
  for (int c0 = 0; c0 < DIMC; c0 += 32) {
    s16x8 ah = *(const s16x8*)(wph + c0);
    s16x8 al = *(const s16x8*)(wpl + c0);
#pragma unroll
    for (int st = 0; st < 4; ++st) {
      s16x8 bh_ = *(const s16x8*)(iph + (size_t)st * 16 * DIMC + c0);
      s16x8 bl_ = *(const s16x8*)(ipl + (size_t)st * 16 * DIMC + c0);
      acc[st] = __builtin_amdgcn_mfma_f32_16x16x32_bf16(ah, bh_, acc[st], 0, 0, 0);
      acc[st] = __builtin_amdgcn_mfma_f32_16x16x32_bf16(ah, bl_, acc[st], 0, 0, 0);
      acc[st] = __builtin_amdgcn_mfma_f32_16x16x32_bf16(al, bh_, acc[st], 0, 0, 0);
    }
  }
#pragma unroll
  for (int st = 0; st < 4; ++st)
#pragma unroll
    for (int r = 0; r < 4; ++r)
      Cl[wave * 16 + g * 4 + r][st * 16 + q] = acc[st][r];
  __syncthreads();

  if (mode == 0) {
    const int o = tid >> 2, nc = (tid & 3) * 16;
    const float bv = bias[o0 + o];
    float* op = outf + ((size_t)b * DIMC + o0 + o) * NPIX + n0 + nc;
#pragma unroll
    for (int i2 = 0; i2 < 4; ++i2) {
      f32x4 v = *(const f32x4*)&Cl[o][nc + i2 * 4];
      v[0] += bv; v[1] += bv; v[2] += bv; v[3] += bv;
      *(f32x4*)(op + i2 * 4) = v;
    }
  } else if (o0 < 256) {
    // Q or K: (C+bias)*scale, hi-only, layout [bh][n][32]
    const int n = tid >> 1, oq = tid & 1;
    const int h = o0 >> 5;
    const float* bp = bias + o0 + oq * 16;
    float v[16];
#pragma unroll
    for (int i = 0; i < 16; ++i) v[i] = (Cl[oq * 16 + i][n] + bp[i]) * scale;
    uint32_t a[16];
#pragma unroll
    for (int i = 0; i < 16; ++i) a[i] = rnau(v[i]);
    union { s16x8 s; uint32_t u[4]; } H0, H1;
#pragma unroll
    for (int j = 0; j < 4; ++j) {
      H0.u[j] = pk2(a[2 * j], a[2 * j + 1]);
      H1.u[j] = pk2(a[8 + 2 * j], a[8 + 2 * j + 1]);
    }
    const size_t off = ((size_t)((b * 8 + h) * NPIX + n0 + n)) * HD + oq * 16;
    *(s16x8*)(d1 + off) = H0.s; *(s16x8*)(d1 + off + 8) = H1.s;
  } else {
    // V hi-only: dst [bh][d][n]
    const int o = tid >> 2, nc = (tid & 3) * 16;
    const int h = (o0 - 256) >> 5;
    const float bv = bias[o0 + o];
    float v[16];
#pragma unroll
    for (int i2 = 0; i2 < 4; ++i2) {
      f32x4 t4 = *(const f32x4*)&Cl[o][nc + i2 * 4];
      v[i2 * 4 + 0] = t4[0] + bv; v[i2 * 4 + 1] = t4[1] + bv;
      v[i2 * 4 + 2] = t4[2] + bv; v[i2 * 4 + 3] = t4[3] + bv;
    }
    uint32_t a[16];
#pragma unroll
    for (int i = 0; i < 16; ++i) a[i] = rnau(v[i]);
    union { s16x8 s; uint32_t u[4]; } H0, H1;
#pragma unroll
    for (int j = 0; j < 4; ++j) {
      H0.u[j] = pk2(a[2 * j], a[2 * j + 1]);
      H1.u[j] = pk2(a[8 + 2 * j], a[8 + 2 * j + 1]);
    }
    const size_t off = ((size_t)((b * 8 + h) * HD + o)) * NPIX + n0 + nc;
    *(s16x8*)(d2 + off) = H0.s; *(s16x8*)(d2 + off + 8) = H1.s;
  }
}

// Combined Q + KV gemm: blockIdx.y 0..7 -> Q (scale), 8..23 -> KV
__global__ __launch_bounds__(128) void gemm_qkv(
    const short* __restrict__ Wth, const short* __restrict__ Wtl,
    const float* __restrict__ q_b, const float* __restrict__ kv_b,
    const short* __restrict__ Xh, const short* __restrict__ Xl,
    const short* __restrict__ Ah, const short* __restrict__ Al,
    short* __restrict__ Qhi, short* __restrict__ Khi, short* __restrict__ Vhi,
    float qscale) {
  __shared__ __align__(16) float Cl[32][68];
  const int by = blockIdx.y;
  if (by < 8) {
    gemm_body(Wth, Wtl, q_b, Xh, Xl, nullptr, Qhi, nullptr,
              2, qscale, blockIdx.x * 64, by * 32, blockIdx.z, Cl);
  } else {
    gemm_body(Wth + 65536, Wtl + 65536, kv_b, Ah, Al, nullptr, Khi, Vhi,
              2, 1.0f, blockIdx.x * 64, (by - 8) * 32, blockIdx.z, Cl);
  }
}

__global__ __launch_bounds__(128) void gemm_proj(
    const short* __restrict__ Wh, const short* __restrict__ Wl,
    const float* __restrict__ bias,
    const short* __restrict__ Zh, const short* __restrict__ Zl,
    float* __restrict__ out) {
  __shared__ __align__(16) float Cl[32][68];
  gemm_body(Wh, Wl, bias, Zh, Zl, out, nullptr, nullptr,
            0, 1.0f, blockIdx.x * 64, blockIdx.y * 32, blockIdx.z, Cl);
}

// ---------------------------------------------------------------------------
// MFMA flash attention, no-max softmax, lag-1 PV pipeline.
// Wave owns TWO 16-row q-tiles (32 q-rows) sharing one K/V fetch stream:
// halves VMEM per unit compute. Q hi only (pre-scaled), K hi, V hi.
// ---------------------------------------------------------------------------
__global__ __launch_bounds__(256) void attn_mfma(
    const short* __restrict__ Qhi,   // [bh][n][32]
    const short* __restrict__ Khi,   // [bh][n][32]
    const short* __restrict__ Vhi,   // [bh][32][N]
    float* __restrict__ part_o,      // [row][NSPLIT][32]
    float* __restrict__ part_l) {    // [row][NSPLIT]
  const int sb = blockIdx.x;        // 0..287
  const int bh = sb / 18;
  const int qb = sb % 18;           // 128-row block
  const int split = blockIdx.y;
  const int tid = threadIdx.x;
  const int wave = tid >> 6, lane = tid & 63;
  const int g = lane >> 4, q = lane & 15;
  const int base = qb * 128 + wave * 32;    // q-rows base for this wave

  __shared__ __align__(16) short Plds[4][2][16 * 40];
  short* pwA = &Plds[wave][0][0];
  short* pwB = &Plds[wave][1][0];

  const size_t qoff = ((size_t)bh * NPIX + base + q) * HD + g * 8;
  const s16x8 qhA = *(const s16x8*)(Qhi + qoff);
  const s16x8 qhB = *(const s16x8*)(Qhi + qoff + 16 * HD);

  const short* kp = Khi + ((size_t)bh * NPIX + split * KPS + q) * HD + g * 8;
  const short* vp = Vhi + ((size_t)bh * HD + q) * NPIX + split * KPS + g * 8;

  f32x4 OA0 = {0,0,0,0}, OA1 = {0,0,0,0}, OB0 = {0,0,0,0}, OB1 = {0,0,0,0};
  float lA = 0.f, lB = 0.f;
  s16x8 kb[2][2], vb[2][2], pfA, pfB, vp0, vp1;

  kb[0][0] = *(const s16x8*)(kp);
  kb[0][1] = *(const s16x8*)(kp + 16 * HD);
  vb[0][0] = *(const s16x8*)(vp);
  vb[0][1] = *(const s16x8*)(vp + 16 * NPIX);

#pragma unroll
  for (int t = 0; t < 18; ++t) {
    const int cur = t & 1, nxt = cur ^ 1;
    if (t < 17) {
      const short* kpn = kp + (t + 1) * (KT * HD);
      const short* vpn = vp + (t + 1) * KT;
      kb[nxt][0] = *(const s16x8*)(kpn);
      kb[nxt][1] = *(const s16x8*)(kpn + 16 * HD);
      vb[nxt][0] = *(const s16x8*)(vpn);
      vb[nxt][1] = *(const s16x8*)(vpn + 16 * NPIX);
    }
    f32x4 SA0 = {0,0,0,0}, SA1 = {0,0,0,0}, SB0 = {0,0,0,0}, SB1 = {0,0,0,0};
    SA0 = __builtin_amdgcn_mfma_f32_16x16x32_bf16(kb[cur][0], qhA, SA0, 0, 0, 0);
    SA1 = __builtin_amdgcn_mfma_f32_16x16x32_bf16(kb[cur][1], qhA, SA1, 0, 0, 0);
    SB0 = __builtin_amdgcn_mfma_f32_16x16x32_bf16(kb[cur][0], qhB, SB0, 0, 0, 0);
    SB1 = __builtin_amdgcn_mfma_f32_16x16x32_bf16(kb[cur][1], qhB, SB1, 0, 0, 0);
    if (t > 0) {   // PV for tile t-1 (pf read issued last iter)
      OA0 = __builtin_amdgcn_mfma_f32_16x16x32_bf16(vp0, pfA, OA0, 0, 0, 0);
      OA1 = __builtin_amdgcn_mfma_f32_16x16x32_bf16(vp1, pfA, OA1, 0, 0, 0);
      OB0 = __builtin_amdgcn_mfma_f32_16x16x32_bf16(vp0, pfB, OB0, 0, 0, 0);
      OB1 = __builtin_amdgcn_mfma_f32_16x16x32_bf16(vp1, pfB, OB1, 0, 0, 0);
    }
    {   // q-tile A softmax weights
      float p[8];
#pragma unroll
      for (int r = 0; r < 4; ++r) { p[r] = exp2f(SA0[r]); p[4 + r] = exp2f(SA1[r]); }
      lA += ((p[0] + p[1]) + (p[2] + p[3])) + ((p[4] + p[5]) + (p[6] + p[7]));
      uint32_t a[8];
#pragma unroll
      for (int r = 0; r < 8; ++r) a[r] = rnau(p[r]);
      uint2 w0, w1;
      w0.x = pk2(a[0], a[1]); w0.y = pk2(a[2], a[3]);
      w1.x = pk2(a[4], a[5]); w1.y = pk2(a[6], a[7]);
      *(uint2*)&pwA[q * 40 + g * 4] = w0;
      *(uint2*)&pwA[q * 40 + 16 + g * 4] = w1;
    }
    {   // q-tile B
      float p[8];
#pragma unroll
      for (int r = 0; r < 4; ++r) { p[r] = exp2f(SB0[r]); p[4 + r] = exp2f(SB1[r]); }
      lB += ((p[0] + p[1]) + (p[2] + p[3])) + ((p[4] + p[5]) + (p[6] + p[7]));
      uint32_t a[8];
#pragma unroll
      for (int r = 0; r < 8; ++r) a[r] = rnau(p[r]);
      uint2 w0, w1;
      w0.x = pk2(a[0], a[1]); w0.y = pk2(a[2], a[3]);
      w1.x = pk2(a[4], a[5]); w1.y = pk2(a[6], a[7]);
      *(uint2*)&pwB[q * 40 + g * 4] = w0;
      *(uint2*)&pwB[q * 40 + 16 + g * 4] = w1;
    }
    vp0 = vb[cur][0]; vp1 = vb[cur][1];
    pfA = *(const s16x8*)&pwA[q * 40 + g * 8];   // consumed next iter
    pfB = *(const s16x8*)&pwB[q * 40 + g * 8];
  }
  OA0 = __builtin_amdgcn_mfma_f32_16x16x32_bf16(vp0, pfA, OA0, 0, 0, 0);
  OA1 = __builtin_amdgcn_mfma_f32_16x16x32_bf16(vp1, pfA, OA1, 0, 0, 0);
  OB0 = __builtin_amdgcn_mfma_f32_16x16x32_bf16(vp0, pfB, OB0, 0, 0, 0);
  OB1 = __builtin_amdgcn_mfma_f32_16x16x32_bf16(vp1, pfB, OB1, 0, 0, 0);

  lA += __shfl_xor(lA, 16); lA += __shfl_xor(lA, 32);
  lB += __shfl_xor(lB, 16); lB += __shfl_xor(lB, 32);

  const int rowA = bh * NPIX + base + q;
  const int rowB = rowA + 16;
  float* poA = part_o + ((size_t)rowA * NSPLIT + split) * HD;
  float* poB = part_o + ((size_t)rowB * NSPLIT + split) * HD;
  *(f32x4*)(poA + g * 4) = OA0;
  *(f32x4*)(poA + 16 + g * 4) = OA1;
  *(f32x4*)(poB + g * 4) = OB0;
  *(f32x4*)(poB + 16 + g * 4) = OB1;
  if (g == 0) {
    part_l[(size_t)rowA * NSPLIT + split] = lA;
    part_l[(size_t)rowB * NSPLIT + split] = lB;
  }
}

// ---------------------------------------------------------------------------
// Merge splits and emit SCRAMBLED z hi/lo [b][p][256]:
// p=(n%9)*256+head*32+dd, c=n/9.
// ---------------------------------------------------------------------------
__global__ __launch_bounds__(288) void attn_merge(const float* __restrict__ part_o,
                                                  const float* __restrict__ part_l,
                                                  short* __restrict__ zh,
                                                  short* __restrict__ zl) {
  const int blk = blockIdx.x;          // 128 = 16 bh * 8
  const int bh = blk >> 3;
  const int n0 = (blk & 7) * 288;
  const int head = bh & 7, b = bh >> 3;
  const int t = threadIdx.x;
  __shared__ __align__(16) float T[288][36];
  {
    const int idx = bh * NPIX + n0 + t;
    f32x4 lv = *(const f32x4*)(part_l + (size_t)idx * NSPLIT);
    const float inv = 1.f / (lv[0] + lv[1] + lv[2] + lv[3]);
    const float* po = part_o + (size_t)idx * (NSPLIT * HD);
#pragma unroll
    for (int u = 0; u < 8; ++u) {
      f32x4 s0 = *(const f32x4*)(po + 0 * HD + u * 4);
      f32x4 s1 = *(const f32x4*)(po + 1 * HD + u * 4);
      f32x4 s2 = *(const f32x4*)(po + 2 * HD + u * 4);
      f32x4 s3 = *(const f32x4*)(po + 3 * HD + u * 4);
      f32x4 v = (s0 + s1) + (s2 + s3);
      v[0] *= inv; v[1] *= inv; v[2] *= inv; v[3] *= inv;
      *(f32x4*)&T[t][u * 4] = v;
    }
  }
  __syncthreads();
  {
    const int r9 = t / 32, dd = t & 31;
    const int p = r9 * 256 + head * HD + dd;
    const int c0 = n0 / 9;
    float v[32];
#pragma unroll
    for (int j = 0; j < 32; ++j) v[j] = T[9 * j + r9][dd];
    uint32_t a[32], al[32];
#pragma unroll
    for (int j = 0; j < 32; ++j) a[j] = rnau(v[j]);
#pragma unroll
    for (int j = 0; j < 32; ++j) al[j] = rnau(v[j] - hif(a[j]));
    const size_t off = ((size_t)b * NPIX + p) * DIMC + c0;
#pragma unroll
    for (int c8 = 0; c8 < 4; ++c8) {
      union { s16x8 s; uint32_t u[4]; } H, L;
#pragma unroll
      for (int j = 0; j < 4; ++j) {
        H.u[j] = pk2(a[c8 * 8 + 2 * j], a[c8 * 8 + 2 * j + 1]);
        L.u[j] = pk2(al[c8 * 8 + 2 * j], al[c8 * 8 + 2 * j + 1]);
      }
      *(s16x8*)(zh + off + c8 * 8) = H.s;
      *(s16x8*)(zl + off + c8 * 8) = L.s;
    }
  }
}

// ---------------------------------------------------------------------------
extern "C" void kernel_launch(void* const* d_in, const int* in_sizes, int n_in,
                              void* d_out, int out_size, void* d_ws, size_t ws_size,
                              hipStream_t stream) {
  const float* x      = (const float*)d_in[0];
  const float* q_w    = (const float*)d_in[1];
  const float* q_b    = (const float*)d_in[2];
  const float* kv_w   = (const float*)d_in[3];
  const float* kv_b   = (const float*)d_in[4];
  const float* proj_w = (const float*)d_in[5];
  const float* proj_b = (const float*)d_in[6];
  float* out = (float*)d_out;

  // Workspace layout (lifetime-aliased, same as R4; Qlo slot now unused):
  //   [0, 18.87MB): xavg + Xh/Xl/Ah/Al during prologue, then part_o (attn)
  char* w = (char*)d_ws;
  float* xavg = (float*)w;                       // 4,718,592 B
  short* Xh   = (short*)(w + 4718592);           // 2,359,296 B each
  short* Xl   = (short*)(w + 7077888);
  short* Ah   = (short*)(w + 9437184);
  short* Al   = (short*)(w + 11796480);
  float* part_o = (float*)w;                     // 18,874,368 B (aliases above)
  short* Wth  = (short*)(w + 18874368);          // 524,288 B
  short* Wtl  = (short*)(w + 19398656);          // 524,288 B
  short* Qhi  = (short*)(w + 19922944);          // 2,359,296 B
  short* Khi  = (short*)(w + 24641536);
  short* Vhi  = (short*)(w + 27000832);
  float* part_l = (float*)(w + 29360128);        // 589,824 B
  short* Zh   = (short*)(w + 29949952);
  short* Zl   = (short*)(w + 32309248);          // ends 34,668,544

  const float qscale = 0.17677669529663689f * 1.4426950408889634f; // d^-0.5*log2(e)

  pool_kernel<<<BATCH * DIMC, 256, 0, stream>>>(x, xavg);
  conv_all<<<704, 256, 0, stream>>>(x, xavg, q_w, kv_w, proj_w,
                                    Xh, Xl, Ah, Al, Wth, Wtl);
  gemm_qkv<<<dim3(36, 24, 2), 128, 0, stream>>>(Wth, Wtl, q_b, kv_b,
                                                Xh, Xl, Ah, Al,
                                                Qhi, Khi, Vhi, qscale);
  attn_mfma<<<dim3(288, NSPLIT), 256, 0, stream>>>(Qhi, Khi, Vhi, part_o, part_l);
  attn_merge<<<128, 288, 0, stream>>>(part_o, part_l, Zh, Zl);
  gemm_proj<<<dim3(36, 8, 2), 128, 0, stream>>>(Wth + 196608, Wtl + 196608, proj_b,
                                                Zh, Zl, out);
}